// Round 2
// 1154.648 us; speedup vs baseline: 1.2327x; 1.2327x over previous
//
#include <hip/hip_runtime.h>

#define Sn 2048
#define Dn 128
#define BHn 32
#define SCALE 0.08838834764831843f  // 1/sqrt(128)

using short8 = __attribute__((ext_vector_type(8))) short;
using f32x16 = __attribute__((ext_vector_type(16))) float;

__device__ inline short rne_bf16(float x) {
  union { float f; unsigned u; } c; c.f = x;
  unsigned r = c.u + 0x7FFFu + ((c.u >> 16) & 1u);
  return (short)(r >> 16);
}

__device__ inline f32x16 zero16() {
  f32x16 z;
#pragma unroll
  for (int i = 0; i < 16; ++i) z[i] = 0.f;
  return z;
}

// Mask dtype detector: int32 0/1 values have byte (4i+1)==0 always; byte bools
// are ~50% nonzero there. flag=1 -> byte mask, flag=0 -> 4-byte words.
__global__ void detect_mask_kernel(const unsigned char* __restrict__ m,
                                   int* __restrict__ flag) {
  if (threadIdx.x == 0) {
    int cnt = 0;
    for (int i = 0; i < 4096; ++i) cnt += (m[i * 4 + 1] != 0);
    *flag = (cnt > 0) ? 1 : 0;
  }
}

// ---------------------------------------------------------------------------
// Pack (attn_mask | window) into bits: bits[(b*S + i)*64 + j/32] bit (j&31).
// 1 MB total -> L2-resident; fused kernel reads one qword per row per 64-tile.
// One dword (32 columns) per thread; grid = B*S*64/256 = 1024 blocks.
// ---------------------------------------------------------------------------
__global__ __launch_bounds__(256) void pack_mask_kernel(
    const unsigned char* __restrict__ m, const int* __restrict__ mflag,
    unsigned* __restrict__ bits) {
  const int idx = blockIdx.x * 256 + threadIdx.x;
  const int word = idx & 63;        // j0/32
  const int i = (idx >> 6) & 2047;  // q row
  const int b = idx >> 17;
  const int j0 = word << 5;
  unsigned v = 0;
  if (*mflag) {  // byte mask
    const unsigned char* base =
        m + ((size_t)b << 22) + ((size_t)i << 11) + j0;
    const uint4* p = (const uint4*)base;
    uint4 a = p[0], c = p[1];
    unsigned wd[8] = {a.x, a.y, a.z, a.w, c.x, c.y, c.z, c.w};
#pragma unroll
    for (int k = 0; k < 8; ++k)
#pragma unroll
      for (int bb = 0; bb < 4; ++bb)
        if ((wd[k] >> (bb * 8)) & 0xFFu) v |= 1u << (k * 4 + bb);
  } else {  // 4-byte words (0/1)
    const unsigned* base =
        (const unsigned*)m + ((size_t)b << 22) + ((size_t)i << 11) + j0;
    const uint4* p = (const uint4*)base;
#pragma unroll
    for (int k = 0; k < 8; ++k) {
      uint4 a = p[k];
      if (a.x) v |= 1u << (k * 4 + 0);
      if (a.y) v |= 1u << (k * 4 + 1);
      if (a.z) v |= 1u << (k * 4 + 2);
      if (a.w) v |= 1u << (k * 4 + 3);
    }
  }
  // fold short-window mask: j < (i*4)/5
  const int wj = (i * 4) / 5;
  if (wj > j0) {
    int nw = wj - j0;
    v |= (nw >= 32) ? 0xFFFFFFFFu : ((1u << nw) - 1u);
  }
  bits[idx] = v;
}

// ---------------------------------------------------------------------------
// Fused attention: per block = 128 q-rows of one (b,h).
// Pass 1: S = Q K^T (bf16 MFMA 32x32x16), e = exp(masked), rowsum in regs.
// Pass 2: recompute S, p = e * inv(rowsum), write attn fp32 once, PV MFMA.
// 4 waves x 32 q-rows. LDS: Kh bf16 chunk-plane layout (bank-balanced b128),
// Vs fp32 pad-132 (conflict-free scalar col reads), Ps per-wave swizzled.
// BITS=1: mask+window come from the packed bitmask (one qword per row per
// 64-col tile, lane-uniform broadcast loads hoisted before staging).
// ---------------------------------------------------------------------------
template <int BITS>
__global__ __launch_bounds__(256, 2) void fused_attn_kernel(
    const float* __restrict__ Q, const float* __restrict__ K,
    const float* __restrict__ V, const void* __restrict__ mask,
    const int* __restrict__ mflag,
    const unsigned long long* __restrict__ mbits, float* __restrict__ attn,
    float* __restrict__ ctx) {
  const int bh = blockIdx.y, b = bh >> 4;
  const int row0 = blockIdx.x << 7;  // 128 rows / block
  const int t = threadIdx.x;
  const int w = t >> 6, lane = t & 63, h = lane >> 5, l32 = lane & 31;
  int msh = 0;
  if (!BITS) msh = (*mflag) ? 0 : 2;

  __shared__ short Kh[16 * 520];     // 16 k-chunk planes, pad 8 shorts/plane
  __shared__ float Vs[64 * 132];     // [j][dv], pad to 132
  __shared__ short Ps[4][1088];      // per-wave p tile 32x32 bf16, swizzled
  __shared__ float inv[128];

  // ---- persistent Q fragments (A-operand: m=l32 row, k = h*8 + j) ----
  short8 qh[8];
  {
    const float* qr = Q + (((size_t)bh << 11) + row0 + (w << 5) + l32) * Dn;
#pragma unroll
    for (int kc = 0; kc < 8; ++kc) {
      const float* p = qr + kc * 16 + h * 8;
      float4 a = *(const float4*)p, bb = *(const float4*)(p + 4);
      short8 v;
      v[0] = rne_bf16(a.x);  v[1] = rne_bf16(a.y);
      v[2] = rne_bf16(a.z);  v[3] = rne_bf16(a.w);
      v[4] = rne_bf16(bb.x); v[5] = rne_bf16(bb.y);
      v[6] = rne_bf16(bb.z); v[7] = rne_bf16(bb.w);
      qh[kc] = v;
    }
  }

  // per-reg row constants (C/D layout: row=(reg&3)+8*(reg>>2)+4*h, col=l32)
  int qi_r[16], wj_r[16];
#pragma unroll
  for (int reg = 0; reg < 16; ++reg) {
    int r = (reg & 3) + ((reg >> 2) << 3) + (h << 2);
    int qi = row0 + (w << 5) + r;
    qi_r[reg] = qi;
    wj_r[reg] = BITS ? 0 : ((qi << 2) / 5);  // window only for legacy path
  }

  const float* Kg = K + (((size_t)bh << 11)) * Dn;
  const float* Vg = V + (((size_t)bh << 11)) * Dn;
  const unsigned char* maskB =
      (const unsigned char*)mask + ((((size_t)b << 11) * Sn) << msh);
  const unsigned long long* Mb = mbits + ((size_t)b << 16);  // b*2048*32 qwords

  float psum[16];
#pragma unroll
  for (int i = 0; i < 16; ++i) psum[i] = 0.f;

  // ======================= PASS 1: row sums =======================
  for (int j0 = 0; j0 < Sn; j0 += 64) {
    unsigned long long mrow[16];
    if (BITS) {
#pragma unroll
      for (int reg = 0; reg < 16; ++reg)
        mrow[reg] = Mb[((size_t)qi_r[reg] << 5) + (j0 >> 6)];
    }
    __syncthreads();
#pragma unroll
    for (int i = 0; i < 4; ++i) {  // stage K chunk -> Kh (bf16)
      int task = t + (i << 8);
      int chunk = task & 15, j = task >> 4;
      const float* src = Kg + (size_t)(j0 + j) * Dn + chunk * 8;
      float4 a = *(const float4*)src, bb = *(const float4*)(src + 4);
      short8 v;
      v[0] = rne_bf16(a.x);  v[1] = rne_bf16(a.y);
      v[2] = rne_bf16(a.z);  v[3] = rne_bf16(a.w);
      v[4] = rne_bf16(bb.x); v[5] = rne_bf16(bb.y);
      v[6] = rne_bf16(bb.z); v[7] = rne_bf16(bb.w);
      *(short8*)&Kh[chunk * 520 + j * 8] = v;
    }
    __syncthreads();
#pragma unroll
    for (int jt = 0; jt < 2; ++jt) {
      f32x16 c = zero16();
#pragma unroll
      for (int kc = 0; kc < 8; ++kc) {
        short8 kb = *(const short8*)&Kh[((kc << 1) + h) * 520 + ((jt << 5) + l32) * 8];
        c = __builtin_amdgcn_mfma_f32_32x32x16_bf16(qh[kc], kb, c, 0, 0, 0);
      }
      const int jv = j0 + (jt << 5) + l32;
#pragma unroll
      for (int reg = 0; reg < 16; ++reg) {
        bool m;
        if (BITS) {
          unsigned half = (unsigned)(mrow[reg] >> (jt << 5));
          m = (half >> l32) & 1u;
        } else {
          int mb = maskB[(size_t)((qi_r[reg] << 11) + jv) << msh];
          m = (mb != 0) | (jv < wj_r[reg]);
        }
        float e = m ? 0.f : __expf(c[reg] * SCALE);
        psum[reg] += e;
      }
    }
  }

  // reduce row sums across the 32 columns held by each half-wave
#pragma unroll
  for (int reg = 0; reg < 16; ++reg) {
    float s = psum[reg];
    s += __shfl_xor(s, 1);  s += __shfl_xor(s, 2);  s += __shfl_xor(s, 4);
    s += __shfl_xor(s, 8);  s += __shfl_xor(s, 16);
    psum[reg] = s;
  }
  if (l32 == 0) {
#pragma unroll
    for (int reg = 0; reg < 16; ++reg) {
      int r = (reg & 3) + ((reg >> 2) << 3) + (h << 2);
      inv[(w << 5) + r] = 1.0f / psum[reg];
    }
  }

  // ======================= PASS 2: write attn + PV =======================
  f32x16 o[4];
#pragma unroll
  for (int i = 0; i < 4; ++i) o[i] = zero16();

  for (int j0 = 0; j0 < Sn; j0 += 64) {
    unsigned long long mrow[16];
    if (BITS) {
#pragma unroll
      for (int reg = 0; reg < 16; ++reg)
        mrow[reg] = Mb[((size_t)qi_r[reg] << 5) + (j0 >> 6)];
    }
    __syncthreads();
#pragma unroll
    for (int i = 0; i < 4; ++i) {  // stage K
      int task = t + (i << 8);
      int chunk = task & 15, j = task >> 4;
      const float* src = Kg + (size_t)(j0 + j) * Dn + chunk * 8;
      float4 a = *(const float4*)src, bb = *(const float4*)(src + 4);
      short8 v;
      v[0] = rne_bf16(a.x);  v[1] = rne_bf16(a.y);
      v[2] = rne_bf16(a.z);  v[3] = rne_bf16(a.w);
      v[4] = rne_bf16(bb.x); v[5] = rne_bf16(bb.y);
      v[6] = rne_bf16(bb.z); v[7] = rne_bf16(bb.w);
      *(short8*)&Kh[chunk * 520 + j * 8] = v;
    }
#pragma unroll
    for (int i = 0; i < 8; ++i) {  // stage V (fp32)
      int task = t + (i << 8);
      int j = task >> 5, dv4 = task & 31;
      *(float4*)&Vs[j * 132 + (dv4 << 2)] =
          *(const float4*)(Vg + (size_t)(j0 + j) * Dn + (dv4 << 2));
    }
    __syncthreads();
#pragma unroll
    for (int jt = 0; jt < 2; ++jt) {
      f32x16 c = zero16();
#pragma unroll
      for (int kc = 0; kc < 8; ++kc) {
        short8 kb = *(const short8*)&Kh[((kc << 1) + h) * 520 + ((jt << 5) + l32) * 8];
        c = __builtin_amdgcn_mfma_f32_32x32x16_bf16(qh[kc], kb, c, 0, 0, 0);
      }
      const int jv = j0 + (jt << 5) + l32;
      // --- compute all p first (no loads between stores and their uses) ---
      float pr[16];
#pragma unroll
      for (int reg = 0; reg < 16; ++reg) {
        int r = (reg & 3) + ((reg >> 2) << 3) + (h << 2);
        bool m;
        if (BITS) {
          unsigned half = (unsigned)(mrow[reg] >> (jt << 5));
          m = (half >> l32) & 1u;
        } else {
          int mb = maskB[(size_t)((qi_r[reg] << 11) + jv) << msh];
          m = (mb != 0) | (jv < wj_r[reg]);
        }
        float e = m ? 0.f : __expf(c[reg] * SCALE);
        pr[reg] = e * inv[(w << 5) + r];
      }
      // --- batched attn stores ---
#pragma unroll
      for (int reg = 0; reg < 16; ++reg)
        attn[((size_t)((bh << 11) + qi_r[reg]) << 11) + jv] = pr[reg];
      // --- batched Ps LDS writes (bf16 truncation, swizzled) ---
#pragma unroll
      for (int reg = 0; reg < 16; ++reg) {
        int r = (reg & 3) + ((reg >> 2) << 3) + (h << 2);
        union { float f; unsigned u; } cc; cc.f = pr[reg];
        Ps[w][(r << 5) + ((r >> 2) << 3) + ((((l32 >> 3) ^ (r & 3))) << 3) + (l32 & 7)] =
            (short)(cc.u >> 16);
      }
      // PV: o[dvt] += P(32 x 32) * V(32 x 128-slice)
#pragma unroll
      for (int kc2 = 0; kc2 < 2; ++kc2) {
        short8 pa = *(const short8*)&Ps[w][(l32 << 5) + ((l32 >> 2) << 3) +
                                           ((((kc2 << 1) + h) ^ (l32 & 3)) << 3)];
        const int jl = (jt << 5) + (kc2 << 4) + (h << 3);
#pragma unroll
        for (int dvt = 0; dvt < 4; ++dvt) {
          const int dv = (dvt << 5) + l32;
          const float* vc = &Vs[jl * 132 + dv];
          unsigned a0 = __float_as_uint(vc[0 * 132]);
          unsigned a1 = __float_as_uint(vc[1 * 132]);
          unsigned a2 = __float_as_uint(vc[2 * 132]);
          unsigned a3 = __float_as_uint(vc[3 * 132]);
          unsigned a4 = __float_as_uint(vc[4 * 132]);
          unsigned a5 = __float_as_uint(vc[5 * 132]);
          unsigned a6 = __float_as_uint(vc[6 * 132]);
          unsigned a7 = __float_as_uint(vc[7 * 132]);
          union { unsigned u[4]; short8 s; } vb;
          vb.u[0] = __builtin_amdgcn_perm(a1, a0, 0x07060302);
          vb.u[1] = __builtin_amdgcn_perm(a3, a2, 0x07060302);
          vb.u[2] = __builtin_amdgcn_perm(a5, a4, 0x07060302);
          vb.u[3] = __builtin_amdgcn_perm(a7, a6, 0x07060302);
          o[dvt] = __builtin_amdgcn_mfma_f32_32x32x16_bf16(pa, vb.s, o[dvt], 0, 0, 0);
        }
      }
    }
  }

  // ---- write context ----
#pragma unroll
  for (int dvt = 0; dvt < 4; ++dvt) {
#pragma unroll
    for (int reg = 0; reg < 16; ++reg) {
      ctx[(((size_t)((bh << 11) + qi_r[reg])) << 7) + (dvt << 5) + l32] =
          o[dvt][reg];
    }
  }
}

// ---------------------------------------------------------------------------
extern "C" void kernel_launch(void* const* d_in, const int* in_sizes, int n_in,
                              void* d_out, int out_size, void* d_ws,
                              size_t ws_size, hipStream_t stream) {
  const float* Q = (const float*)d_in[0];
  const float* K = (const float*)d_in[1];
  const float* V = (const float*)d_in[2];
  const void* mask = d_in[3];

  float* out = (float*)d_out;
  float* ctx = out;                                  // B*H*S*DV
  float* attn = out + (size_t)BHn * Sn * (size_t)Dn; // B*H*S*S

  int* mflag = (int*)d_ws;
  unsigned* bits32 = (unsigned*)((char*)d_ws + 64);
  const size_t bits_bytes = (size_t)2 * Sn * (Sn / 8);  // B*S*S/8 = 1 MiB

  detect_mask_kernel<<<1, 64, 0, stream>>>((const unsigned char*)mask, mflag);

  dim3 grid(Sn / 128, BHn);
  if (ws_size >= bits_bytes + 128) {
    // pack mask|window into bits: B*S*64 dwords / 256 threads = 1024 blocks
    pack_mask_kernel<<<dim3(1024), 256, 0, stream>>>(
        (const unsigned char*)mask, mflag, bits32);
    fused_attn_kernel<1><<<grid, 256, 0, stream>>>(
        Q, K, V, mask, mflag, (const unsigned long long*)bits32, attn, ctx);
  } else {
    fused_attn_kernel<0><<<grid, 256, 0, stream>>>(
        Q, K, V, mask, mflag, nullptr, attn, ctx);
  }
}

// Round 6
// 1152.899 us; speedup vs baseline: 1.2345x; 1.0015x over previous
//
#include <hip/hip_runtime.h>

#define Sn 2048
#define Dn 128
#define BHn 32
#define SCALE 0.08838834764831843f  // 1/sqrt(128)

using short8 = __attribute__((ext_vector_type(8))) short;
using f32x16 = __attribute__((ext_vector_type(16))) float;

__device__ __forceinline__ short rne_bf16(float x) {
  union { float f; unsigned u; } c; c.f = x;
  unsigned r = c.u + 0x7FFFu + ((c.u >> 16) & 1u);
  return (short)(r >> 16);
}

__device__ __forceinline__ f32x16 zero16() {
  f32x16 z;
#pragma unroll
  for (int i = 0; i < 16; ++i) z[i] = 0.f;
  return z;
}

// Mask dtype detector: int32 0/1 values have byte (4i+1)==0 always; byte bools
// are ~50% nonzero there. flag=1 -> byte mask, flag=0 -> 4-byte words.
__global__ void detect_mask_kernel(const unsigned char* __restrict__ m,
                                   int* __restrict__ flag) {
  if (threadIdx.x == 0) {
    int cnt = 0;
    for (int i = 0; i < 4096; ++i) cnt += (m[i * 4 + 1] != 0);
    *flag = (cnt > 0) ? 1 : 0;
  }
}

// ---------------------------------------------------------------------------
// Pack (attn_mask | window) into bits: bits[(b*S + i)*64 + j/32] bit (j&31).
// 1 MB total -> L2-resident; fused kernel reads one dword per row per 32-cols.
// ---------------------------------------------------------------------------
__global__ __launch_bounds__(256) void pack_mask_kernel(
    const unsigned char* __restrict__ m, const int* __restrict__ mflag,
    unsigned* __restrict__ bits) {
  const int idx = blockIdx.x * 256 + threadIdx.x;
  const int word = idx & 63;        // j0/32
  const int i = (idx >> 6) & 2047;  // q row
  const int b = idx >> 17;
  const int j0 = word << 5;
  unsigned v = 0;
  if (*mflag) {  // byte mask
    const unsigned char* base =
        m + ((size_t)b << 22) + ((size_t)i << 11) + j0;
    const uint4* p = (const uint4*)base;
    uint4 a = p[0], c = p[1];
    unsigned wd[8] = {a.x, a.y, a.z, a.w, c.x, c.y, c.z, c.w};
#pragma unroll
    for (int k = 0; k < 8; ++k)
#pragma unroll
      for (int bb = 0; bb < 4; ++bb)
        if ((wd[k] >> (bb * 8)) & 0xFFu) v |= 1u << (k * 4 + bb);
  } else {  // 4-byte words (0/1)
    const unsigned* base =
        (const unsigned*)m + ((size_t)b << 22) + ((size_t)i << 11) + j0;
    const uint4* p = (const uint4*)base;
#pragma unroll
    for (int k = 0; k < 8; ++k) {
      uint4 a = p[k];
      if (a.x) v |= 1u << (k * 4 + 0);
      if (a.y) v |= 1u << (k * 4 + 1);
      if (a.z) v |= 1u << (k * 4 + 2);
      if (a.w) v |= 1u << (k * 4 + 3);
    }
  }
  // fold short-window mask: j < (i*4)/5
  const int wj = (i * 4) / 5;
  if (wj > j0) {
    int nw = wj - j0;
    v |= (nw >= 32) ? 0xFFFFFFFFu : ((1u << nw) - 1u);
  }
  bits[idx] = v;
}

// ---------------------------------------------------------------------------
// Staging helpers. All indices compile-time after unroll.
// K thread task: chunk = t&15 (8-float dk slice), rows j = (t>>4) + 16*i.
// V thread task: dv4 = t&31 (4 dv cols), rows j = (t>>5)*8 + i (8 consecutive).
// ---------------------------------------------------------------------------
__device__ __forceinline__ void kload(const float* __restrict__ Kg, int j0,
                                      int kjb, int kchunk, float4 (&kp)[8]) {
#pragma unroll
  for (int i = 0; i < 4; ++i) {
    const float* src = Kg + (size_t)(j0 + kjb + (i << 4)) * Dn + kchunk * 8;
    kp[2 * i] = *(const float4*)src;
    kp[2 * i + 1] = *(const float4*)(src + 4);
  }
}

__device__ __forceinline__ void kstore(short* Kh, int kjb, int kchunk,
                                       const float4 (&kp)[8]) {
#pragma unroll
  for (int i = 0; i < 4; ++i) {
    short8 v;
    v[0] = rne_bf16(kp[2 * i].x);     v[1] = rne_bf16(kp[2 * i].y);
    v[2] = rne_bf16(kp[2 * i].z);     v[3] = rne_bf16(kp[2 * i].w);
    v[4] = rne_bf16(kp[2 * i + 1].x); v[5] = rne_bf16(kp[2 * i + 1].y);
    v[6] = rne_bf16(kp[2 * i + 1].z); v[7] = rne_bf16(kp[2 * i + 1].w);
    *(short8*)&Kh[kchunk * 520 + (kjb + (i << 4)) * 8] = v;
  }
}

__device__ __forceinline__ void vload(const float* __restrict__ Vg, int j0,
                                      int vjb, int vdv4, float4 (&vp)[8]) {
#pragma unroll
  for (int i = 0; i < 8; ++i)
    vp[i] =
        *(const float4*)(Vg + (size_t)(j0 + (vjb << 3) + i) * Dn + (vdv4 << 2));
}

// V transposed bf16 [dv][64 j], row = 128B, 16B-block XOR swizzle by (dv&7):
// write b128 conflict-free; PV reads become single b128 per MFMA operand.
__device__ __forceinline__ void vstore(short* Vsb, int vjb, int vdv4,
                                       const float4 (&vp)[8]) {
#pragma unroll
  for (int r = 0; r < 4; ++r) {
    short8 vv;
#pragma unroll
    for (int i = 0; i < 8; ++i) {
      float f = (r == 0) ? vp[i].x
                : (r == 1) ? vp[i].y
                : (r == 2) ? vp[i].z : vp[i].w;
      vv[i] = rne_bf16(f);
    }
    const int dv = (vdv4 << 2) + r;
    *(short8*)((char*)Vsb + (dv << 7) + ((vjb << 4) ^ ((dv & 7) << 4))) = vv;
  }
}

// ---------------------------------------------------------------------------
// v3: register-prefetch pipeline with STANDARD __syncthreads() barriers.
// Per iter: [sync] write regs->LDS [sync] issue prefetch(t+1) -> compute(t).
// Prefetch loads get the whole compute phase (~2.5k cycles) to retire before
// the next barrier's vmcnt drain, so the drain waits on retired ops.
// V staged transposed bf16 (one ds_read_b128 per PV B-operand);
// inv held in registers (every lane owns its row sums after shuffle reduce).
// ---------------------------------------------------------------------------
__global__ __launch_bounds__(256, 2) void fused_attn_v3(
    const float* __restrict__ Q, const float* __restrict__ K,
    const float* __restrict__ V, const unsigned* __restrict__ mbw,
    float* __restrict__ attn, float* __restrict__ ctx) {
  const int bh = blockIdx.y, b = bh >> 4;
  const int row0 = blockIdx.x << 7;  // 128 q-rows / block
  const int t = threadIdx.x;
  const int w = t >> 6, lane = t & 63, h = lane >> 5, l32 = lane & 31;

  __shared__ short Kh[16 * 520];   // 16 k-chunk planes, pad 8 shorts/plane
  __shared__ short Vsb[128 * 64];  // [dv][j] bf16, XOR-swizzled 16B blocks
  __shared__ short Ps[4][1088];    // per-wave p tile 32x32 bf16, swizzled

  // ---- persistent Q fragments (A-operand: m=l32 row, k = h*8 + j) ----
  short8 qh[8];
  {
    const float* qr = Q + (((size_t)bh << 11) + row0 + (w << 5) + l32) * Dn;
#pragma unroll
    for (int kc = 0; kc < 8; ++kc) {
      const float* p = qr + kc * 16 + h * 8;
      float4 a = *(const float4*)p, bb = *(const float4*)(p + 4);
      short8 v;
      v[0] = rne_bf16(a.x);  v[1] = rne_bf16(a.y);
      v[2] = rne_bf16(a.z);  v[3] = rne_bf16(a.w);
      v[4] = rne_bf16(bb.x); v[5] = rne_bf16(bb.y);
      v[6] = rne_bf16(bb.z); v[7] = rne_bf16(bb.w);
      qh[kc] = v;
    }
  }

  const float* Kg = K + ((size_t)bh << 11) * Dn;
  const float* Vg = V + ((size_t)bh << 11) * Dn;
  const unsigned* Mw = mbw + ((size_t)b << 17);  // b * 2048 * 64 dwords

  const int kchunk = t & 15, kjb = t >> 4;
  const int vdv4 = t & 31, vjb = t >> 5;

  float psum[16];
#pragma unroll
  for (int i = 0; i < 16; ++i) psum[i] = 0.f;

  float4 kp[8];
  kload(Kg, 0, kjb, kchunk, kp);  // prologue prefetch

  // ======================= PASS 1: row sums =======================
  for (int j0 = 0; j0 < Sn; j0 += 64) {
    __syncthreads();                 // tile t-1 readers done
    kstore(Kh, kjb, kchunk, kp);     // counted vmcnt wait on kp here
    __syncthreads();                 // tile t visible
    if (j0 + 64 < Sn) kload(Kg, j0 + 64, kjb, kchunk, kp);  // prefetch t+1
#pragma unroll
    for (int jt = 0; jt < 2; ++jt) {
      const unsigned* mp =
          Mw + (((size_t)(row0 + (w << 5))) << 6) + (j0 >> 5) + jt;
      unsigned mw[16];
#pragma unroll
      for (int reg = 0; reg < 16; ++reg) {
        int r = (reg & 3) + ((reg >> 2) << 3) + (h << 2);
        mw[reg] = mp[(size_t)r << 6];
      }
      f32x16 c = zero16();
#pragma unroll
      for (int kc = 0; kc < 8; ++kc) {
        short8 kb =
            *(const short8*)&Kh[((kc << 1) + h) * 520 + ((jt << 5) + l32) * 8];
        c = __builtin_amdgcn_mfma_f32_32x32x16_bf16(qh[kc], kb, c, 0, 0, 0);
      }
#pragma unroll
      for (int reg = 0; reg < 16; ++reg) {
        bool m = (mw[reg] >> l32) & 1u;
        float e = m ? 0.f : __expf(c[reg] * SCALE);
        psum[reg] += e;
      }
    }
  }

  // shuffle-reduce across 32 columns; every lane keeps its rows' inverses.
  float inv_r[16];
#pragma unroll
  for (int reg = 0; reg < 16; ++reg) {
    float s = psum[reg];
    s += __shfl_xor(s, 1);  s += __shfl_xor(s, 2);  s += __shfl_xor(s, 4);
    s += __shfl_xor(s, 8);  s += __shfl_xor(s, 16);
    inv_r[reg] = 1.0f / s;
  }

  // ======================= PASS 2: write attn + PV =======================
  f32x16 o[4];
#pragma unroll
  for (int i = 0; i < 4; ++i) o[i] = zero16();

  float4 vp[8];
  kload(Kg, 0, kjb, kchunk, kp);
  vload(Vg, 0, vjb, vdv4, vp);

  for (int j0 = 0; j0 < Sn; j0 += 64) {
    __syncthreads();
    kstore(Kh, kjb, kchunk, kp);
    vstore(Vsb, vjb, vdv4, vp);
    __syncthreads();
    if (j0 + 64 < Sn) {
      kload(Kg, j0 + 64, kjb, kchunk, kp);
      vload(Vg, j0 + 64, vjb, vdv4, vp);
    }
#pragma unroll
    for (int jt = 0; jt < 2; ++jt) {
      const unsigned* mp =
          Mw + (((size_t)(row0 + (w << 5))) << 6) + (j0 >> 5) + jt;
      unsigned mw[16];
#pragma unroll
      for (int reg = 0; reg < 16; ++reg) {
        int r = (reg & 3) + ((reg >> 2) << 3) + (h << 2);
        mw[reg] = mp[(size_t)r << 6];
      }
      f32x16 c = zero16();
#pragma unroll
      for (int kc = 0; kc < 8; ++kc) {
        short8 kb =
            *(const short8*)&Kh[((kc << 1) + h) * 520 + ((jt << 5) + l32) * 8];
        c = __builtin_amdgcn_mfma_f32_32x32x16_bf16(qh[kc], kb, c, 0, 0, 0);
      }
      const int jv = j0 + (jt << 5) + l32;
      // --- compute all p first ---
      float pr[16];
#pragma unroll
      for (int reg = 0; reg < 16; ++reg) {
        bool m = (mw[reg] >> l32) & 1u;
        float e = m ? 0.f : __expf(c[reg] * SCALE);
        pr[reg] = e * inv_r[reg];
      }
      // --- batched attn stores ---
      const size_t abase = (((size_t)(bh << 11) + row0 + (w << 5)) << 11) + jv;
#pragma unroll
      for (int reg = 0; reg < 16; ++reg) {
        int r = (reg & 3) + ((reg >> 2) << 3) + (h << 2);
        attn[abase + ((size_t)r << 11)] = pr[reg];
      }
      // --- batched Ps LDS writes (bf16 truncation, swizzled) ---
#pragma unroll
      for (int reg = 0; reg < 16; ++reg) {
        int r = (reg & 3) + ((reg >> 2) << 3) + (h << 2);
        union { float f; unsigned u; } cc; cc.f = pr[reg];
        Ps[w][(r << 5) + ((r >> 2) << 3) + ((((l32 >> 3) ^ (r & 3))) << 3) +
              (l32 & 7)] = (short)(cc.u >> 16);
      }
      // PV: o[dvt] += P(32x32) * V(32x128) -- V operand is one b128 each.
#pragma unroll
      for (int kc2 = 0; kc2 < 2; ++kc2) {
        short8 pa = *(const short8*)&Ps[w][(l32 << 5) + ((l32 >> 2) << 3) +
                                           ((((kc2 << 1) + h) ^ (l32 & 3)) << 3)];
        const int jb3 = (jt << 2) + (kc2 << 1) + h;  // j-block index (8 rows)
#pragma unroll
        for (int dvt = 0; dvt < 4; ++dvt) {
          const int dv = (dvt << 5) + l32;
          short8 vb = *(const short8*)((const char*)Vsb + (dv << 7) +
                                       ((jb3 << 4) ^ ((l32 & 7) << 4)));
          o[dvt] = __builtin_amdgcn_mfma_f32_32x32x16_bf16(pa, vb, o[dvt], 0, 0, 0);
        }
      }
    }
  }

  // ---- write context ----
  const size_t cbase = ((size_t)(bh << 11) + row0 + (w << 5)) << 7;
#pragma unroll
  for (int dvt = 0; dvt < 4; ++dvt) {
#pragma unroll
    for (int reg = 0; reg < 16; ++reg) {
      int r = (reg & 3) + ((reg >> 2) << 3) + (h << 2);
      ctx[cbase + ((size_t)r << 7) + (dvt << 5) + l32] = o[dvt][reg];
    }
  }
}

// ---------------------------------------------------------------------------
// Legacy fallback (round-2 kernel, BITS=0 path): used only if workspace is
// too small for the bitmask. Known-correct.
// ---------------------------------------------------------------------------
__global__ __launch_bounds__(256, 2) void fused_attn_legacy(
    const float* __restrict__ Q, const float* __restrict__ K,
    const float* __restrict__ V, const void* __restrict__ mask,
    const int* __restrict__ mflag, float* __restrict__ attn,
    float* __restrict__ ctx) {
  const int bh = blockIdx.y, b = bh >> 4;
  const int row0 = blockIdx.x << 7;
  const int t = threadIdx.x;
  const int w = t >> 6, lane = t & 63, h = lane >> 5, l32 = lane & 31;
  const int msh = (*mflag) ? 0 : 2;

  __shared__ short Kh[16 * 520];
  __shared__ float Vs[64 * 132];
  __shared__ short Ps[4][1088];
  __shared__ float inv[128];

  short8 qh[8];
  {
    const float* qr = Q + (((size_t)bh << 11) + row0 + (w << 5) + l32) * Dn;
#pragma unroll
    for (int kc = 0; kc < 8; ++kc) {
      const float* p = qr + kc * 16 + h * 8;
      float4 a = *(const float4*)p, bb = *(const float4*)(p + 4);
      short8 v;
      v[0] = rne_bf16(a.x);  v[1] = rne_bf16(a.y);
      v[2] = rne_bf16(a.z);  v[3] = rne_bf16(a.w);
      v[4] = rne_bf16(bb.x); v[5] = rne_bf16(bb.y);
      v[6] = rne_bf16(bb.z); v[7] = rne_bf16(bb.w);
      qh[kc] = v;
    }
  }

  int qi_r[16], wj_r[16];
#pragma unroll
  for (int reg = 0; reg < 16; ++reg) {
    int r = (reg & 3) + ((reg >> 2) << 3) + (h << 2);
    int qi = row0 + (w << 5) + r;
    qi_r[reg] = qi;
    wj_r[reg] = (qi << 2) / 5;
  }

  const float* Kg = K + (((size_t)bh << 11)) * Dn;
  const float* Vg = V + (((size_t)bh << 11)) * Dn;
  const unsigned char* maskB =
      (const unsigned char*)mask + ((((size_t)b << 11) * Sn) << msh);

  float psum[16];
#pragma unroll
  for (int i = 0; i < 16; ++i) psum[i] = 0.f;

  for (int j0 = 0; j0 < Sn; j0 += 64) {
    __syncthreads();
#pragma unroll
    for (int i = 0; i < 4; ++i) {
      int task = t + (i << 8);
      int chunk = task & 15, j = task >> 4;
      const float* src = Kg + (size_t)(j0 + j) * Dn + chunk * 8;
      float4 a = *(const float4*)src, bb = *(const float4*)(src + 4);
      short8 v;
      v[0] = rne_bf16(a.x);  v[1] = rne_bf16(a.y);
      v[2] = rne_bf16(a.z);  v[3] = rne_bf16(a.w);
      v[4] = rne_bf16(bb.x); v[5] = rne_bf16(bb.y);
      v[6] = rne_bf16(bb.z); v[7] = rne_bf16(bb.w);
      *(short8*)&Kh[chunk * 520 + j * 8] = v;
    }
    __syncthreads();
#pragma unroll
    for (int jt = 0; jt < 2; ++jt) {
      f32x16 c = zero16();
#pragma unroll
      for (int kc = 0; kc < 8; ++kc) {
        short8 kb = *(const short8*)&Kh[((kc << 1) + h) * 520 + ((jt << 5) + l32) * 8];
        c = __builtin_amdgcn_mfma_f32_32x32x16_bf16(qh[kc], kb, c, 0, 0, 0);
      }
      const int jv = j0 + (jt << 5) + l32;
#pragma unroll
      for (int reg = 0; reg < 16; ++reg) {
        int mb = maskB[(size_t)((qi_r[reg] << 11) + jv) << msh];
        bool m = (mb != 0) | (jv < wj_r[reg]);
        float e = m ? 0.f : __expf(c[reg] * SCALE);
        psum[reg] += e;
      }
    }
  }

#pragma unroll
  for (int reg = 0; reg < 16; ++reg) {
    float s = psum[reg];
    s += __shfl_xor(s, 1);  s += __shfl_xor(s, 2);  s += __shfl_xor(s, 4);
    s += __shfl_xor(s, 8);  s += __shfl_xor(s, 16);
    psum[reg] = s;
  }
  if (l32 == 0) {
#pragma unroll
    for (int reg = 0; reg < 16; ++reg) {
      int r = (reg & 3) + ((reg >> 2) << 3) + (h << 2);
      inv[(w << 5) + r] = 1.0f / psum[reg];
    }
  }

  f32x16 o[4];
#pragma unroll
  for (int i = 0; i < 4; ++i) o[i] = zero16();

  for (int j0 = 0; j0 < Sn; j0 += 64) {
    __syncthreads();
#pragma unroll
    for (int i = 0; i < 4; ++i) {
      int task = t + (i << 8);
      int chunk = task & 15, j = task >> 4;
      const float* src = Kg + (size_t)(j0 + j) * Dn + chunk * 8;
      float4 a = *(const float4*)src, bb = *(const float4*)(src + 4);
      short8 v;
      v[0] = rne_bf16(a.x);  v[1] = rne_bf16(a.y);
      v[2] = rne_bf16(a.z);  v[3] = rne_bf16(a.w);
      v[4] = rne_bf16(bb.x); v[5] = rne_bf16(bb.y);
      v[6] = rne_bf16(bb.z); v[7] = rne_bf16(bb.w);
      *(short8*)&Kh[chunk * 520 + j * 8] = v;
    }
#pragma unroll
    for (int i = 0; i < 8; ++i) {
      int task = t + (i << 8);
      int j = task >> 5, dv4 = task & 31;
      *(float4*)&Vs[j * 132 + (dv4 << 2)] =
          *(const float4*)(Vg + (size_t)(j0 + j) * Dn + (dv4 << 2));
    }
    __syncthreads();
#pragma unroll
    for (int jt = 0; jt < 2; ++jt) {
      f32x16 c = zero16();
#pragma unroll
      for (int kc = 0; kc < 8; ++kc) {
        short8 kb = *(const short8*)&Kh[((kc << 1) + h) * 520 + ((jt << 5) + l32) * 8];
        c = __builtin_amdgcn_mfma_f32_32x32x16_bf16(qh[kc], kb, c, 0, 0, 0);
      }
      const int jv = j0 + (jt << 5) + l32;
      float pr[16];
#pragma unroll
      for (int reg = 0; reg < 16; ++reg) {
        int r = (reg & 3) + ((reg >> 2) << 3) + (h << 2);
        int mb = maskB[(size_t)((qi_r[reg] << 11) + jv) << msh];
        bool m = (mb != 0) | (jv < wj_r[reg]);
        float e = m ? 0.f : __expf(c[reg] * SCALE);
        pr[reg] = e * inv[(w << 5) + r];
      }
#pragma unroll
      for (int reg = 0; reg < 16; ++reg)
        attn[((size_t)((bh << 11) + qi_r[reg]) << 11) + jv] = pr[reg];
#pragma unroll
      for (int reg = 0; reg < 16; ++reg) {
        int r = (reg & 3) + ((reg >> 2) << 3) + (h << 2);
        union { float f; unsigned u; } cc; cc.f = pr[reg];
        Ps[w][(r << 5) + ((r >> 2) << 3) + ((((l32 >> 3) ^ (r & 3))) << 3) + (l32 & 7)] =
            (short)(cc.u >> 16);
      }
#pragma unroll
      for (int kc2 = 0; kc2 < 2; ++kc2) {
        short8 pa = *(const short8*)&Ps[w][(l32 << 5) + ((l32 >> 2) << 3) +
                                           ((((kc2 << 1) + h) ^ (l32 & 3)) << 3)];
        const int jl = (jt << 5) + (kc2 << 4) + (h << 3);
#pragma unroll
        for (int dvt = 0; dvt < 4; ++dvt) {
          const int dv = (dvt << 5) + l32;
          const float* vc = &Vs[jl * 132 + dv];
          unsigned a0 = __float_as_uint(vc[0 * 132]);
          unsigned a1 = __float_as_uint(vc[1 * 132]);
          unsigned a2 = __float_as_uint(vc[2 * 132]);
          unsigned a3 = __float_as_uint(vc[3 * 132]);
          unsigned a4 = __float_as_uint(vc[4 * 132]);
          unsigned a5 = __float_as_uint(vc[5 * 132]);
          unsigned a6 = __float_as_uint(vc[6 * 132]);
          unsigned a7 = __float_as_uint(vc[7 * 132]);
          union { unsigned u[4]; short8 s; } vb;
          vb.u[0] = __builtin_amdgcn_perm(a1, a0, 0x07060302);
          vb.u[1] = __builtin_amdgcn_perm(a3, a2, 0x07060302);
          vb.u[2] = __builtin_amdgcn_perm(a5, a4, 0x07060302);
          vb.u[3] = __builtin_amdgcn_perm(a7, a6, 0x07060302);
          o[dvt] = __builtin_amdgcn_mfma_f32_32x32x16_bf16(pa, vb.s, o[dvt], 0, 0, 0);
        }
      }
    }
  }

#pragma unroll
  for (int dvt = 0; dvt < 4; ++dvt) {
#pragma unroll
    for (int reg = 0; reg < 16; ++reg) {
      ctx[(((size_t)((bh << 11) + qi_r[reg])) << 7) + (dvt << 5) + l32] =
          o[dvt][reg];
    }
  }
}

// ---------------------------------------------------------------------------
extern "C" void kernel_launch(void* const* d_in, const int* in_sizes, int n_in,
                              void* d_out, int out_size, void* d_ws,
                              size_t ws_size, hipStream_t stream) {
  const float* Q = (const float*)d_in[0];
  const float* K = (const float*)d_in[1];
  const float* V = (const float*)d_in[2];
  const void* mask = d_in[3];

  float* out = (float*)d_out;
  float* ctx = out;                                  // B*H*S*DV
  float* attn = out + (size_t)BHn * Sn * (size_t)Dn; // B*H*S*S

  int* mflag = (int*)d_ws;
  unsigned* bits32 = (unsigned*)((char*)d_ws + 64);
  const size_t bits_bytes = (size_t)2 * Sn * (Sn / 8);  // B*S*S/8 = 1 MiB

  detect_mask_kernel<<<1, 64, 0, stream>>>((const unsigned char*)mask, mflag);

  dim3 grid(Sn / 128, BHn);
  if (ws_size >= bits_bytes + 128) {
    pack_mask_kernel<<<dim3(1024), 256, 0, stream>>>(
        (const unsigned char*)mask, mflag, bits32);
    fused_attn_v3<<<grid, 256, 0, stream>>>(Q, K, V, bits32, attn, ctx);
  } else {
    fused_attn_legacy<<<grid, 256, 0, stream>>>(Q, K, V, mask, mflag, attn,
                                                ctx);
  }
}

// Round 7
// 882.925 us; speedup vs baseline: 1.6120x; 1.3058x over previous
//
#include <hip/hip_runtime.h>

#define Sn 2048
#define Dn 128
#define BHn 32
#define NT 32                 // 64-row k-tiles per sequence
#define TILE_SHORTS 8192      // 16 KB bf16 tile (64 j x 128 d)
#define SCALE 0.08838834764831843f  // 1/sqrt(128)

using short8 = __attribute__((ext_vector_type(8))) short;
using f32x16 = __attribute__((ext_vector_type(16))) float;

__device__ __forceinline__ short rne_bf16(float x) {
  union { float f; unsigned u; } c; c.f = x;
  unsigned r = c.u + 0x7FFFu + ((c.u >> 16) & 1u);
  return (short)(r >> 16);
}

__device__ __forceinline__ f32x16 zero16() {
  f32x16 z;
#pragma unroll
  for (int i = 0; i < 16; ++i) z[i] = 0.f;
  return z;
}

// Mask dtype detector: int32 0/1 values have byte (4i+1)==0 always; byte bools
// are ~50% nonzero there. flag=1 -> byte mask, flag=0 -> 4-byte words.
__global__ void detect_mask_kernel(const unsigned char* __restrict__ m,
                                   int* __restrict__ flag) {
  if (threadIdx.x == 0) {
    int cnt = 0;
    for (int i = 0; i < 4096; ++i) cnt += (m[i * 4 + 1] != 0);
    *flag = (cnt > 0) ? 1 : 0;
  }
}

// ---------------------------------------------------------------------------
// Pack (attn_mask | window) into bits: bits[(b*S + i)*64 + j/32] bit (j&31).
// 1 MB total -> L2-resident.
// ---------------------------------------------------------------------------
__global__ __launch_bounds__(256) void pack_mask_kernel(
    const unsigned char* __restrict__ m, const int* __restrict__ mflag,
    unsigned* __restrict__ bits) {
  const int idx = blockIdx.x * 256 + threadIdx.x;
  const int word = idx & 63;        // j0/32
  const int i = (idx >> 6) & 2047;  // q row
  const int b = idx >> 17;
  const int j0 = word << 5;
  unsigned v = 0;
  if (*mflag) {  // byte mask
    const unsigned char* base =
        m + ((size_t)b << 22) + ((size_t)i << 11) + j0;
    const uint4* p = (const uint4*)base;
    uint4 a = p[0], c = p[1];
    unsigned wd[8] = {a.x, a.y, a.z, a.w, c.x, c.y, c.z, c.w};
#pragma unroll
    for (int k = 0; k < 8; ++k)
#pragma unroll
      for (int bb = 0; bb < 4; ++bb)
        if ((wd[k] >> (bb * 8)) & 0xFFu) v |= 1u << (k * 4 + bb);
  } else {  // 4-byte words (0/1)
    const unsigned* base =
        (const unsigned*)m + ((size_t)b << 22) + ((size_t)i << 11) + j0;
    const uint4* p = (const uint4*)base;
#pragma unroll
    for (int k = 0; k < 8; ++k) {
      uint4 a = p[k];
      if (a.x) v |= 1u << (k * 4 + 0);
      if (a.y) v |= 1u << (k * 4 + 1);
      if (a.z) v |= 1u << (k * 4 + 2);
      if (a.w) v |= 1u << (k * 4 + 3);
    }
  }
  const int wj = (i * 4) / 5;  // short-window: j < wj masked
  if (wj > j0) {
    int nw = wj - j0;
    v |= (nw >= 32) ? 0xFFFFFFFFu : ((1u << nw) - 1u);
  }
  bits[idx] = v;
}

// ---------------------------------------------------------------------------
// Pre-pack K -> bf16 tiles. Tile layout (16 KB): 16 planes p (8 dk each) x
// 64 j x 16B chunk. Byte off = p*1024 + j*16. Matches fused-kernel LDS layout
// so staging is a pure linear b128 copy.
// ---------------------------------------------------------------------------
__global__ __launch_bounds__(256) void pack_k_kernel(
    const float* __restrict__ K, short* __restrict__ Kpk) {
  const int tile = blockIdx.x, bh = blockIdx.y;
  const int t = threadIdx.x;
  __shared__ float Kf[64 * 132];
  const float* src = K + ((size_t)bh * Sn + (size_t)tile * 64) * Dn;
#pragma unroll
  for (int i = 0; i < 8; ++i) {  // coalesced stage: 2048 float4
    int c = t + (i << 8);
    int j = c >> 5, f4 = c & 31;
    *(float4*)&Kf[j * 132 + (f4 << 2)] =
        *(const float4*)(src + (size_t)j * Dn + (f4 << 2));
  }
  __syncthreads();
  short* dst = Kpk + ((size_t)bh * NT + tile) * TILE_SHORTS;
#pragma unroll
  for (int i = 0; i < 4; ++i) {
    int c = t + (i << 8);  // chunk: p = c>>6, j = c&63  (write coalesced)
    int p = c >> 6, j = c & 63;
    const float* row = &Kf[j * 132 + (p << 3)];
    short8 v;
#pragma unroll
    for (int k = 0; k < 8; ++k) v[k] = rne_bf16(row[k]);
    *(short8*)&dst[(size_t)c << 3] = v;
  }
}

// ---------------------------------------------------------------------------
// Pre-pack V -> bf16 transposed tiles [dv][j] with 16B XOR swizzle by (dv&7):
// byte off = dv*128 + ((jo*16) ^ ((dv&7)*16)), chunk jo holds j = jo*8..+7.
// Fused PV read (dv = dvt*32+l32) is then a single b128, ~4-way max conflict.
// ---------------------------------------------------------------------------
__global__ __launch_bounds__(256) void pack_v_kernel(
    const float* __restrict__ V, short* __restrict__ Vt) {
  const int tile = blockIdx.x, bh = blockIdx.y;
  const int t = threadIdx.x;
  __shared__ float Vf[64 * 132];
  const float* src = V + ((size_t)bh * Sn + (size_t)tile * 64) * Dn;
#pragma unroll
  for (int i = 0; i < 8; ++i) {
    int c = t + (i << 8);
    int j = c >> 5, f4 = c & 31;
    *(float4*)&Vf[j * 132 + (f4 << 2)] =
        *(const float4*)(src + (size_t)j * Dn + (f4 << 2));
  }
  __syncthreads();
  short* dst = Vt + ((size_t)bh * NT + tile) * TILE_SHORTS;
#pragma unroll
  for (int i = 0; i < 4; ++i) {
    int c = t + (i << 8);  // chunk: dv = c>>3, jo = c&7
    int dv = c >> 3, jo = c & 7;
    short8 v;
#pragma unroll
    for (int k = 0; k < 8; ++k) v[k] = rne_bf16(Vf[(jo * 8 + k) * 132 + dv]);
    *(short8*)((char*)dst + (dv << 7) + ((jo << 4) ^ ((dv & 7) << 4))) = v;
  }
}

// ---------------------------------------------------------------------------
// v4: traffic-optimized fused attention.
//  - K/V read as pre-packed bf16 (half the refetch bytes, zero cvt VALU).
//  - XCD swizzle: all 16 blocks of one bh land on one XCD -> 4 panels/XCD
//    (4 MB bf16) fit L2; K/V rereads become L2 hits.
//  - Nontemporal attn/ctx stores (don't evict K/V from L2).
//  - Window skip: tiles entirely left of every row's window are skipped
//    (zero-filled in pass 2), ~37% less K/V traffic + QK compute on average.
//  - Double-buffered LDS, one __syncthreads per tile, prefetch-top /
//    ds_write-bottom (T14 split: HBM latency hides under compute).
// ---------------------------------------------------------------------------
__global__ __launch_bounds__(256, 2) void fused_attn_v4(
    const float* __restrict__ Q, const short* __restrict__ Kpk,
    const short* __restrict__ Vt, const unsigned* __restrict__ mbw,
    float* __restrict__ attn, float* __restrict__ ctx) {
  const int flat = blockIdx.x;
  // XCD swizzle: flat%8 == bh%8 -> per XCD only 4 distinct bh panels.
  const int bh = (flat & 7) + (((flat >> 3) & 3) << 3);
  const int bx = flat >> 5;
  const int b = bh >> 4;
  const int row0 = bx << 7;  // 128 q-rows / block
  const int t = threadIdx.x;
  const int w = t >> 6, lane = t & 63, h = lane >> 5, l32 = lane & 31;

  __shared__ short Kbuf[2][TILE_SHORTS];  // 2 x 16 KB
  __shared__ short Vbuf[2][TILE_SHORTS];  // 2 x 16 KB
  __shared__ short Ps[4][1088];           // per-wave P tile, swizzled

  // ---- persistent Q fragments (A-operand: m=l32 row, k = h*8 + j) ----
  short8 qh[8];
  {
    const float* qr = Q + (((size_t)bh << 11) + row0 + (w << 5) + l32) * Dn;
#pragma unroll
    for (int kc = 0; kc < 8; ++kc) {
      const float* p = qr + kc * 16 + h * 8;
      float4 a = *(const float4*)p, bb = *(const float4*)(p + 4);
      short8 v;
      v[0] = rne_bf16(a.x);  v[1] = rne_bf16(a.y);
      v[2] = rne_bf16(a.z);  v[3] = rne_bf16(a.w);
      v[4] = rne_bf16(bb.x); v[5] = rne_bf16(bb.y);
      v[6] = rne_bf16(bb.z); v[7] = rne_bf16(bb.w);
      qh[kc] = v;
    }
  }

  const short* Kg = Kpk + (size_t)bh * NT * TILE_SHORTS;
  const short* Vg = Vt + (size_t)bh * NT * TILE_SHORTS;
  const unsigned* Mw = mbw + ((size_t)b << 17);  // b * 2048 * 64 dwords

  // window skip: tiles [0, t_start) have j0+63 < (row0*4)/5 <= every row's
  // window start -> fully masked for all 128 rows of this block.
  const int t_start = ((row0 * 4) / 5) >> 6;

  float psum[16];
#pragma unroll
  for (int i = 0; i < 16; ++i) psum[i] = 0.f;

  short8 kreg[4], vreg[4];

  // ======================= PASS 1: row sums =======================
#pragma unroll
  for (int i = 0; i < 4; ++i)
    kreg[i] = *(const short8*)&Kg[((size_t)t_start << 13) + ((t + (i << 8)) << 3)];
#pragma unroll
  for (int i = 0; i < 4; ++i)
    *(short8*)&Kbuf[0][(t + (i << 8)) << 3] = kreg[i];
  __syncthreads();

  for (int tt = t_start; tt < NT; ++tt) {
    const int cur = (tt - t_start) & 1;
    if (tt + 1 < NT) {  // prefetch next tile into regs (latency under compute)
#pragma unroll
      for (int i = 0; i < 4; ++i)
        kreg[i] =
            *(const short8*)&Kg[((size_t)(tt + 1) << 13) + ((t + (i << 8)) << 3)];
    }
    const int j0 = tt << 6;
#pragma unroll
    for (int jt = 0; jt < 2; ++jt) {
      const unsigned* mp =
          Mw + (((size_t)(row0 + (w << 5))) << 6) + (j0 >> 5) + jt;
      unsigned mw[16];
#pragma unroll
      for (int reg = 0; reg < 16; ++reg) {
        int r = (reg & 3) + ((reg >> 2) << 3) + (h << 2);
        mw[reg] = mp[(size_t)r << 6];
      }
      f32x16 c = zero16();
      __builtin_amdgcn_s_setprio(1);
#pragma unroll
      for (int kc = 0; kc < 8; ++kc) {
        short8 kb = *(const short8*)&Kbuf[cur][(((kc << 1) + h) << 9) +
                                              (((jt << 5) + l32) << 3)];
        c = __builtin_amdgcn_mfma_f32_32x32x16_bf16(qh[kc], kb, c, 0, 0, 0);
      }
      __builtin_amdgcn_s_setprio(0);
#pragma unroll
      for (int reg = 0; reg < 16; ++reg) {
        bool m = (mw[reg] >> l32) & 1u;
        float e = m ? 0.f : __expf(c[reg] * SCALE);
        psum[reg] += e;
      }
    }
    if (tt + 1 < NT) {
#pragma unroll
      for (int i = 0; i < 4; ++i)
        *(short8*)&Kbuf[cur ^ 1][(t + (i << 8)) << 3] = kreg[i];
    }
    __syncthreads();
  }

  // shuffle-reduce across 32 columns; every lane keeps its rows' inverses.
  float inv_r[16];
#pragma unroll
  for (int reg = 0; reg < 16; ++reg) {
    float s = psum[reg];
    s += __shfl_xor(s, 1);  s += __shfl_xor(s, 2);  s += __shfl_xor(s, 4);
    s += __shfl_xor(s, 8);  s += __shfl_xor(s, 16);
    inv_r[reg] = 1.0f / s;
  }

  // ======================= PASS 2: write attn + PV =======================
  f32x16 o[4];
#pragma unroll
  for (int i = 0; i < 4; ++i) o[i] = zero16();

  // prologue loads for tile t_start (issued before zero-fill to hide latency)
#pragma unroll
  for (int i = 0; i < 4; ++i) {
    kreg[i] = *(const short8*)&Kg[((size_t)t_start << 13) + ((t + (i << 8)) << 3)];
    vreg[i] = *(const short8*)&Vg[((size_t)t_start << 13) + ((t + (i << 8)) << 3)];
  }

  // zero-fill attn over the fully-window-masked tiles
  for (int tt = 0; tt < t_start; ++tt) {
    const int j0 = tt << 6;
#pragma unroll
    for (int jt = 0; jt < 2; ++jt) {
      const int jv = j0 + (jt << 5) + l32;
      const size_t abase = (((size_t)(bh << 11) + row0 + (w << 5)) << 11) + jv;
#pragma unroll
      for (int reg = 0; reg < 16; ++reg) {
        int r = (reg & 3) + ((reg >> 2) << 3) + (h << 2);
        __builtin_nontemporal_store(0.f, &attn[abase + ((size_t)r << 11)]);
      }
    }
  }

#pragma unroll
  for (int i = 0; i < 4; ++i) {
    *(short8*)&Kbuf[0][(t + (i << 8)) << 3] = kreg[i];
    *(short8*)&Vbuf[0][(t + (i << 8)) << 3] = vreg[i];
  }
  __syncthreads();

  for (int tt = t_start; tt < NT; ++tt) {
    const int cur = (tt - t_start) & 1;
    if (tt + 1 < NT) {
#pragma unroll
      for (int i = 0; i < 4; ++i) {
        kreg[i] =
            *(const short8*)&Kg[((size_t)(tt + 1) << 13) + ((t + (i << 8)) << 3)];
        vreg[i] =
            *(const short8*)&Vg[((size_t)(tt + 1) << 13) + ((t + (i << 8)) << 3)];
      }
    }
    const int j0 = tt << 6;
#pragma unroll
    for (int jt = 0; jt < 2; ++jt) {
      const unsigned* mp =
          Mw + (((size_t)(row0 + (w << 5))) << 6) + (j0 >> 5) + jt;
      unsigned mw[16];
#pragma unroll
      for (int reg = 0; reg < 16; ++reg) {
        int r = (reg & 3) + ((reg >> 2) << 3) + (h << 2);
        mw[reg] = mp[(size_t)r << 6];
      }
      f32x16 c = zero16();
      __builtin_amdgcn_s_setprio(1);
#pragma unroll
      for (int kc = 0; kc < 8; ++kc) {
        short8 kb = *(const short8*)&Kbuf[cur][(((kc << 1) + h) << 9) +
                                              (((jt << 5) + l32) << 3)];
        c = __builtin_amdgcn_mfma_f32_32x32x16_bf16(qh[kc], kb, c, 0, 0, 0);
      }
      __builtin_amdgcn_s_setprio(0);
      const int jv = j0 + (jt << 5) + l32;
      // --- compute all p first ---
      float pr[16];
#pragma unroll
      for (int reg = 0; reg < 16; ++reg) {
        bool m = (mw[reg] >> l32) & 1u;
        float e = m ? 0.f : __expf(c[reg] * SCALE);
        pr[reg] = e * inv_r[reg];
      }
      // --- batched nontemporal attn stores ---
      const size_t abase = (((size_t)(bh << 11) + row0 + (w << 5)) << 11) + jv;
#pragma unroll
      for (int reg = 0; reg < 16; ++reg) {
        int r = (reg & 3) + ((reg >> 2) << 3) + (h << 2);
        __builtin_nontemporal_store(pr[reg], &attn[abase + ((size_t)r << 11)]);
      }
      // --- batched Ps LDS writes (bf16 truncation, swizzled) ---
#pragma unroll
      for (int reg = 0; reg < 16; ++reg) {
        int r = (reg & 3) + ((reg >> 2) << 3) + (h << 2);
        union { float f; unsigned u; } cc; cc.f = pr[reg];
        Ps[w][(r << 5) + ((r >> 2) << 3) + ((((l32 >> 3) ^ (r & 3))) << 3) +
              (l32 & 7)] = (short)(cc.u >> 16);
      }
      // PV: o[dvt] += P(32x32) * V(32x128); V operand is one b128 each.
      __builtin_amdgcn_s_setprio(1);
#pragma unroll
      for (int kc2 = 0; kc2 < 2; ++kc2) {
        short8 pa = *(const short8*)&Ps[w][(l32 << 5) + ((l32 >> 2) << 3) +
                                           ((((kc2 << 1) + h) ^ (l32 & 3)) << 3)];
        const int jb3 = (jt << 2) + (kc2 << 1) + h;  // 8-row j-block index
#pragma unroll
        for (int dvt = 0; dvt < 4; ++dvt) {
          const int dv = (dvt << 5) + l32;
          short8 vb = *(const short8*)((const char*)&Vbuf[cur][0] + (dv << 7) +
                                       ((jb3 << 4) ^ ((l32 & 7) << 4)));
          o[dvt] = __builtin_amdgcn_mfma_f32_32x32x16_bf16(pa, vb, o[dvt], 0, 0, 0);
        }
      }
      __builtin_amdgcn_s_setprio(0);
    }
    if (tt + 1 < NT) {
#pragma unroll
      for (int i = 0; i < 4; ++i) {
        *(short8*)&Kbuf[cur ^ 1][(t + (i << 8)) << 3] = kreg[i];
        *(short8*)&Vbuf[cur ^ 1][(t + (i << 8)) << 3] = vreg[i];
      }
    }
    __syncthreads();
  }

  // ---- write context (nontemporal) ----
  const size_t cbase = ((size_t)(bh << 11) + row0 + (w << 5)) << 7;
#pragma unroll
  for (int dvt = 0; dvt < 4; ++dvt) {
#pragma unroll
    for (int reg = 0; reg < 16; ++reg) {
      int r = (reg & 3) + ((reg >> 2) << 3) + (h << 2);
      __builtin_nontemporal_store(
          o[dvt][reg], &ctx[cbase + ((size_t)r << 7) + (dvt << 5) + l32]);
    }
  }
}

// ---------------------------------------------------------------------------
// v3 fallback (measured 520 us): used if workspace too small for K/V packs.
// ---------------------------------------------------------------------------
__device__ __forceinline__ void kload(const float* __restrict__ Kg, int j0,
                                      int kjb, int kchunk, float4 (&kp)[8]) {
#pragma unroll
  for (int i = 0; i < 4; ++i) {
    const float* src = Kg + (size_t)(j0 + kjb + (i << 4)) * Dn + kchunk * 8;
    kp[2 * i] = *(const float4*)src;
    kp[2 * i + 1] = *(const float4*)(src + 4);
  }
}

__device__ __forceinline__ void kstore(short* Kh, int kjb, int kchunk,
                                       const float4 (&kp)[8]) {
#pragma unroll
  for (int i = 0; i < 4; ++i) {
    short8 v;
    v[0] = rne_bf16(kp[2 * i].x);     v[1] = rne_bf16(kp[2 * i].y);
    v[2] = rne_bf16(kp[2 * i].z);     v[3] = rne_bf16(kp[2 * i].w);
    v[4] = rne_bf16(kp[2 * i + 1].x); v[5] = rne_bf16(kp[2 * i + 1].y);
    v[6] = rne_bf16(kp[2 * i + 1].z); v[7] = rne_bf16(kp[2 * i + 1].w);
    *(short8*)&Kh[kchunk * 520 + (kjb + (i << 4)) * 8] = v;
  }
}

__device__ __forceinline__ void vload(const float* __restrict__ Vg, int j0,
                                      int vjb, int vdv4, float4 (&vp)[8]) {
#pragma unroll
  for (int i = 0; i < 8; ++i)
    vp[i] =
        *(const float4*)(Vg + (size_t)(j0 + (vjb << 3) + i) * Dn + (vdv4 << 2));
}

__device__ __forceinline__ void vstore(short* Vsb, int vjb, int vdv4,
                                       const float4 (&vp)[8]) {
#pragma unroll
  for (int r = 0; r < 4; ++r) {
    short8 vv;
#pragma unroll
    for (int i = 0; i < 8; ++i) {
      float f = (r == 0) ? vp[i].x
                : (r == 1) ? vp[i].y
                : (r == 2) ? vp[i].z : vp[i].w;
      vv[i] = rne_bf16(f);
    }
    const int dv = (vdv4 << 2) + r;
    *(short8*)((char*)Vsb + (dv << 7) + ((vjb << 4) ^ ((dv & 7) << 4))) = vv;
  }
}

__global__ __launch_bounds__(256, 2) void fused_attn_v3(
    const float* __restrict__ Q, const float* __restrict__ K,
    const float* __restrict__ V, const unsigned* __restrict__ mbw,
    float* __restrict__ attn, float* __restrict__ ctx) {
  const int bh = blockIdx.y, b = bh >> 4;
  const int row0 = blockIdx.x << 7;
  const int t = threadIdx.x;
  const int w = t >> 6, lane = t & 63, h = lane >> 5, l32 = lane & 31;

  __shared__ short Kh[16 * 520];
  __shared__ short Vsb[128 * 64];
  __shared__ short Ps[4][1088];

  short8 qh[8];
  {
    const float* qr = Q + (((size_t)bh << 11) + row0 + (w << 5) + l32) * Dn;
#pragma unroll
    for (int kc = 0; kc < 8; ++kc) {
      const float* p = qr + kc * 16 + h * 8;
      float4 a = *(const float4*)p, bb = *(const float4*)(p + 4);
      short8 v;
      v[0] = rne_bf16(a.x);  v[1] = rne_bf16(a.y);
      v[2] = rne_bf16(a.z);  v[3] = rne_bf16(a.w);
      v[4] = rne_bf16(bb.x); v[5] = rne_bf16(bb.y);
      v[6] = rne_bf16(bb.z); v[7] = rne_bf16(bb.w);
      qh[kc] = v;
    }
  }

  const float* Kg = K + ((size_t)bh << 11) * Dn;
  const float* Vg = V + ((size_t)bh << 11) * Dn;
  const unsigned* Mw = mbw + ((size_t)b << 17);

  const int kchunk = t & 15, kjb = t >> 4;
  const int vdv4 = t & 31, vjb = t >> 5;

  float psum[16];
#pragma unroll
  for (int i = 0; i < 16; ++i) psum[i] = 0.f;

  float4 kp[8];
  kload(Kg, 0, kjb, kchunk, kp);

  for (int j0 = 0; j0 < Sn; j0 += 64) {
    __syncthreads();
    kstore(Kh, kjb, kchunk, kp);
    __syncthreads();
    if (j0 + 64 < Sn) kload(Kg, j0 + 64, kjb, kchunk, kp);
#pragma unroll
    for (int jt = 0; jt < 2; ++jt) {
      const unsigned* mp =
          Mw + (((size_t)(row0 + (w << 5))) << 6) + (j0 >> 5) + jt;
      unsigned mw[16];
#pragma unroll
      for (int reg = 0; reg < 16; ++reg) {
        int r = (reg & 3) + ((reg >> 2) << 3) + (h << 2);
        mw[reg] = mp[(size_t)r << 6];
      }
      f32x16 c = zero16();
#pragma unroll
      for (int kc = 0; kc < 8; ++kc) {
        short8 kb =
            *(const short8*)&Kh[((kc << 1) + h) * 520 + ((jt << 5) + l32) * 8];
        c = __builtin_amdgcn_mfma_f32_32x32x16_bf16(qh[kc], kb, c, 0, 0, 0);
      }
#pragma unroll
      for (int reg = 0; reg < 16; ++reg) {
        bool m = (mw[reg] >> l32) & 1u;
        float e = m ? 0.f : __expf(c[reg] * SCALE);
        psum[reg] += e;
      }
    }
  }

  float inv_r[16];
#pragma unroll
  for (int reg = 0; reg < 16; ++reg) {
    float s = psum[reg];
    s += __shfl_xor(s, 1);  s += __shfl_xor(s, 2);  s += __shfl_xor(s, 4);
    s += __shfl_xor(s, 8);  s += __shfl_xor(s, 16);
    inv_r[reg] = 1.0f / s;
  }

  f32x16 o[4];
#pragma unroll
  for (int i = 0; i < 4; ++i) o[i] = zero16();

  float4 vp[8];
  kload(Kg, 0, kjb, kchunk, kp);
  vload(Vg, 0, vjb, vdv4, vp);

  for (int j0 = 0; j0 < Sn; j0 += 64) {
    __syncthreads();
    kstore(Kh, kjb, kchunk, kp);
    vstore(Vsb, vjb, vdv4, vp);
    __syncthreads();
    if (j0 + 64 < Sn) {
      kload(Kg, j0 + 64, kjb, kchunk, kp);
      vload(Vg, j0 + 64, vjb, vdv4, vp);
    }
#pragma unroll
    for (int jt = 0; jt < 2; ++jt) {
      const unsigned* mp =
          Mw + (((size_t)(row0 + (w << 5))) << 6) + (j0 >> 5) + jt;
      unsigned mw[16];
#pragma unroll
      for (int reg = 0; reg < 16; ++reg) {
        int r = (reg & 3) + ((reg >> 2) << 3) + (h << 2);
        mw[reg] = mp[(size_t)r << 6];
      }
      f32x16 c = zero16();
#pragma unroll
      for (int kc = 0; kc < 8; ++kc) {
        short8 kb =
            *(const short8*)&Kh[((kc << 1) + h) * 520 + ((jt << 5) + l32) * 8];
        c = __builtin_amdgcn_mfma_f32_32x32x16_bf16(qh[kc], kb, c, 0, 0, 0);
      }
      const int jv = j0 + (jt << 5) + l32;
      float pr[16];
#pragma unroll
      for (int reg = 0; reg < 16; ++reg) {
        bool m = (mw[reg] >> l32) & 1u;
        float e = m ? 0.f : __expf(c[reg] * SCALE);
        pr[reg] = e * inv_r[reg];
      }
      const size_t abase = (((size_t)(bh << 11) + row0 + (w << 5)) << 11) + jv;
#pragma unroll
      for (int reg = 0; reg < 16; ++reg) {
        int r = (reg & 3) + ((reg >> 2) << 3) + (h << 2);
        attn[abase + ((size_t)r << 11)] = pr[reg];
      }
#pragma unroll
      for (int reg = 0; reg < 16; ++reg) {
        int r = (reg & 3) + ((reg >> 2) << 3) + (h << 2);
        union { float f; unsigned u; } cc; cc.f = pr[reg];
        Ps[w][(r << 5) + ((r >> 2) << 3) + ((((l32 >> 3) ^ (r & 3))) << 3) +
              (l32 & 7)] = (short)(cc.u >> 16);
      }
#pragma unroll
      for (int kc2 = 0; kc2 < 2; ++kc2) {
        short8 pa = *(const short8*)&Ps[w][(l32 << 5) + ((l32 >> 2) << 3) +
                                           ((((kc2 << 1) + h) ^ (l32 & 3)) << 3)];
        const int jb3 = (jt << 2) + (kc2 << 1) + h;
#pragma unroll
        for (int dvt = 0; dvt < 4; ++dvt) {
          const int dv = (dvt << 5) + l32;
          short8 vb = *(const short8*)((const char*)Vsb + (dv << 7) +
                                       ((jb3 << 4) ^ ((l32 & 7) << 4)));
          o[dvt] = __builtin_amdgcn_mfma_f32_32x32x16_bf16(pa, vb, o[dvt], 0, 0, 0);
        }
      }
    }
  }

  const size_t cbase = ((size_t)(bh << 11) + row0 + (w << 5)) << 7;
#pragma unroll
  for (int dvt = 0; dvt < 4; ++dvt) {
#pragma unroll
    for (int reg = 0; reg < 16; ++reg) {
      int r = (reg & 3) + ((reg >> 2) << 3) + (h << 2);
      ctx[cbase + ((size_t)r << 7) + (dvt << 5) + l32] = o[dvt][reg];
    }
  }
}

// ---------------------------------------------------------------------------
extern "C" void kernel_launch(void* const* d_in, const int* in_sizes, int n_in,
                              void* d_out, int out_size, void* d_ws,
                              size_t ws_size, hipStream_t stream) {
  const float* Q = (const float*)d_in[0];
  const float* K = (const float*)d_in[1];
  const float* V = (const float*)d_in[2];
  const void* mask = d_in[3];

  float* out = (float*)d_out;
  float* ctx = out;                                   // B*H*S*DV
  float* attn = out + (size_t)BHn * Sn * (size_t)Dn;  // B*H*S*S

  int* mflag = (int*)d_ws;
  unsigned* bits32 = (unsigned*)((char*)d_ws + 256);
  const size_t bits_bytes = (size_t)2 * Sn * (Sn / 8);  // 1 MiB
  short* Kpk = (short*)((char*)d_ws + 256 + bits_bytes);
  const size_t pack_shorts = (size_t)BHn * NT * TILE_SHORTS;  // 8.4M shorts
  short* Vt = Kpk + pack_shorts;
  const size_t need_v4 = 256 + bits_bytes + 2 * pack_shorts * sizeof(short);

  detect_mask_kernel<<<1, 64, 0, stream>>>((const unsigned char*)mask, mflag);

  if (ws_size >= need_v4) {
    pack_mask_kernel<<<dim3(1024), 256, 0, stream>>>(
        (const unsigned char*)mask, mflag, bits32);
    pack_k_kernel<<<dim3(NT, BHn), 256, 0, stream>>>(K, Kpk);
    pack_v_kernel<<<dim3(NT, BHn), 256, 0, stream>>>(V, Vt);
    fused_attn_v4<<<dim3(512), 256, 0, stream>>>(Q, Kpk, Vt, bits32, attn,
                                                 ctx);
  } else {
    pack_mask_kernel<<<dim3(1024), 256, 0, stream>>>(
        (const unsigned char*)mask, mflag, bits32);
    fused_attn_v3<<<dim3(Sn / 128, BHn), 256, 0, stream>>>(Q, K, V, bits32,
                                                           attn, ctx);
  }
}

// Round 8
// 763.641 us; speedup vs baseline: 1.8638x; 1.1562x over previous
//
#include <hip/hip_runtime.h>

#define Sn 2048
#define Dn 128
#define BHn 32
#define NT 32                 // 64-row k-tiles per sequence
#define TILE_SHORTS 8192      // 16 KB bf16 tile (64 j x 128 d)
#define SCALE 0.08838834764831843f  // 1/sqrt(128)

using short8 = __attribute__((ext_vector_type(8))) short;
using f32x16 = __attribute__((ext_vector_type(16))) float;

__device__ __forceinline__ short rne_bf16(float x) {
  union { float f; unsigned u; } c; c.f = x;
  unsigned r = c.u + 0x7FFFu + ((c.u >> 16) & 1u);
  return (short)(r >> 16);
}

__device__ __forceinline__ f32x16 zero16() {
  f32x16 z;
#pragma unroll
  for (int i = 0; i < 16; ++i) z[i] = 0.f;
  return z;
}

// Mask dtype detector (PARALLEL: 64 lanes, ballot-reduce). int32 0/1 masks
// have byte (4i+1)==0 always; byte bools are ~50% nonzero there.
__global__ void detect_mask_kernel(const unsigned char* __restrict__ m,
                                   int* __restrict__ flag) {
  const int t = threadIdx.x;  // 64 threads = 1 wave
  int cnt = 0;
  for (int i = t; i < 4096; i += 64) cnt += (m[i * 4 + 1] != 0);
  unsigned long long any = __ballot(cnt > 0);
  if (t == 0) *flag = (any != 0ull) ? 1 : 0;
}

// ---------------------------------------------------------------------------
// Pack (attn_mask | window) into bits: bits[(b*S + i)*64 + j/32] bit (j&31).
// 1 MB total -> L2-resident.
// ---------------------------------------------------------------------------
__global__ __launch_bounds__(256) void pack_mask_kernel(
    const unsigned char* __restrict__ m, const int* __restrict__ mflag,
    unsigned* __restrict__ bits) {
  const int idx = blockIdx.x * 256 + threadIdx.x;
  const int word = idx & 63;        // j0/32
  const int i = (idx >> 6) & 2047;  // q row
  const int b = idx >> 17;
  const int j0 = word << 5;
  unsigned v = 0;
  if (*mflag) {  // byte mask
    const unsigned char* base =
        m + ((size_t)b << 22) + ((size_t)i << 11) + j0;
    const uint4* p = (const uint4*)base;
    uint4 a = p[0], c = p[1];
    unsigned wd[8] = {a.x, a.y, a.z, a.w, c.x, c.y, c.z, c.w};
#pragma unroll
    for (int k = 0; k < 8; ++k)
#pragma unroll
      for (int bb = 0; bb < 4; ++bb)
        if ((wd[k] >> (bb * 8)) & 0xFFu) v |= 1u << (k * 4 + bb);
  } else {  // 4-byte words (0/1)
    const unsigned* base =
        (const unsigned*)m + ((size_t)b << 22) + ((size_t)i << 11) + j0;
    const uint4* p = (const uint4*)base;
#pragma unroll
    for (int k = 0; k < 8; ++k) {
      uint4 a = p[k];
      if (a.x) v |= 1u << (k * 4 + 0);
      if (a.y) v |= 1u << (k * 4 + 1);
      if (a.z) v |= 1u << (k * 4 + 2);
      if (a.w) v |= 1u << (k * 4 + 3);
    }
  }
  const int wj = (i * 4) / 5;  // short-window: j < wj masked
  if (wj > j0) {
    int nw = wj - j0;
    v |= (nw >= 32) ? 0xFFFFFFFFu : ((1u << nw) - 1u);
  }
  bits[idx] = v;
}

// ---------------------------------------------------------------------------
// Pre-pack K -> bf16 tiles. Tile layout (16 KB): 16 planes p (8 dk each) x
// 64 j x 16B chunk. Byte off = p*1024 + j*16. Matches fused-kernel LDS layout
// so staging is a pure linear b128 copy.
// ---------------------------------------------------------------------------
__global__ __launch_bounds__(256) void pack_k_kernel(
    const float* __restrict__ K, short* __restrict__ Kpk) {
  const int tile = blockIdx.x, bh = blockIdx.y;
  const int t = threadIdx.x;
  __shared__ float Kf[64 * 132];
  const float* src = K + ((size_t)bh * Sn + (size_t)tile * 64) * Dn;
#pragma unroll
  for (int i = 0; i < 8; ++i) {  // coalesced stage: 2048 float4
    int c = t + (i << 8);
    int j = c >> 5, f4 = c & 31;
    *(float4*)&Kf[j * 132 + (f4 << 2)] =
        *(const float4*)(src + (size_t)j * Dn + (f4 << 2));
  }
  __syncthreads();
  short* dst = Kpk + ((size_t)bh * NT + tile) * TILE_SHORTS;
#pragma unroll
  for (int i = 0; i < 4; ++i) {
    int c = t + (i << 8);  // chunk: p = c>>6, j = c&63  (write coalesced)
    int p = c >> 6, j = c & 63;
    const float* row = &Kf[j * 132 + (p << 3)];
    short8 v;
#pragma unroll
    for (int k = 0; k < 8; ++k) v[k] = rne_bf16(row[k]);
    *(short8*)&dst[(size_t)c << 3] = v;
  }
}

// ---------------------------------------------------------------------------
// Pre-pack V -> bf16 transposed tiles [dv][j] with 16B XOR swizzle by (dv&7):
// byte off = dv*128 + ((jo*16) ^ ((dv&7)*16)), chunk jo holds j = jo*8..+7.
// Fused PV read (dv = dvt*32+l32) is then a single b128, ~4-way max conflict.
// ---------------------------------------------------------------------------
__global__ __launch_bounds__(256) void pack_v_kernel(
    const float* __restrict__ V, short* __restrict__ Vt) {
  const int tile = blockIdx.x, bh = blockIdx.y;
  const int t = threadIdx.x;
  __shared__ float Vf[64 * 132];
  const float* src = V + ((size_t)bh * Sn + (size_t)tile * 64) * Dn;
#pragma unroll
  for (int i = 0; i < 8; ++i) {
    int c = t + (i << 8);
    int j = c >> 5, f4 = c & 31;
    *(float4*)&Vf[j * 132 + (f4 << 2)] =
        *(const float4*)(src + (size_t)j * Dn + (f4 << 2));
  }
  __syncthreads();
  short* dst = Vt + ((size_t)bh * NT + tile) * TILE_SHORTS;
#pragma unroll
  for (int i = 0; i < 4; ++i) {
    int c = t + (i << 8);  // chunk: dv = c>>3, jo = c&7
    int dv = c >> 3, jo = c & 7;
    short8 v;
#pragma unroll
    for (int k = 0; k < 8; ++k) v[k] = rne_bf16(Vf[(jo * 8 + k) * 132 + dv]);
    *(short8*)((char*)dst + (dv << 7) + ((jo << 4) ^ ((dv & 7) << 4))) = v;
  }
}

// ---------------------------------------------------------------------------
// v5: v4 + balanced per-CU work pairing.
// Breadth-first dispatch model: XCD = flat%8, then round-robin over CUs;
// CU c on an XCD receives in-XCD sequence numbers n and n+32. Mapping
//   x = flat&7, n = flat>>3, s = n>>5, r = n&31,
//   bh = x + 8*(r&3), bx = s ? 15-(r>>2) : (r>>2)
// gives each CU the block pair (bx, 15-bx) of the SAME bh: per-CU work
// ~= const (40 tile-units) instead of 28.8..51.2 (1.66x spread), and both
// resident blocks share one K/V panel (better L2). Pure permutation --
// correctness independent of the dispatch model.
// ---------------------------------------------------------------------------
__global__ __launch_bounds__(256, 2) void fused_attn_v5(
    const float* __restrict__ Q, const short* __restrict__ Kpk,
    const short* __restrict__ Vt, const unsigned* __restrict__ mbw,
    float* __restrict__ attn, float* __restrict__ ctx) {
  const int flat = blockIdx.x;
  const int x = flat & 7;
  const int n = flat >> 3;
  const int s = n >> 5;
  const int r = n & 31;
  const int bh = x + ((r & 3) << 3);
  const int bx = s ? (15 - (r >> 2)) : (r >> 2);
  const int b = bh >> 4;
  const int row0 = bx << 7;  // 128 q-rows / block
  const int t = threadIdx.x;
  const int w = t >> 6, lane = t & 63, h = lane >> 5, l32 = lane & 31;

  __shared__ short Kbuf[2][TILE_SHORTS];  // 2 x 16 KB
  __shared__ short Vbuf[2][TILE_SHORTS];  // 2 x 16 KB
  __shared__ short Ps[4][1088];           // per-wave P tile, swizzled

  // ---- persistent Q fragments (A-operand: m=l32 row, k = h*8 + j) ----
  short8 qh[8];
  {
    const float* qr = Q + (((size_t)bh << 11) + row0 + (w << 5) + l32) * Dn;
#pragma unroll
    for (int kc = 0; kc < 8; ++kc) {
      const float* p = qr + kc * 16 + h * 8;
      float4 a = *(const float4*)p, bb = *(const float4*)(p + 4);
      short8 v;
      v[0] = rne_bf16(a.x);  v[1] = rne_bf16(a.y);
      v[2] = rne_bf16(a.z);  v[3] = rne_bf16(a.w);
      v[4] = rne_bf16(bb.x); v[5] = rne_bf16(bb.y);
      v[6] = rne_bf16(bb.z); v[7] = rne_bf16(bb.w);
      qh[kc] = v;
    }
  }

  const short* Kg = Kpk + (size_t)bh * NT * TILE_SHORTS;
  const short* Vg = Vt + (size_t)bh * NT * TILE_SHORTS;
  const unsigned* Mw = mbw + ((size_t)b << 17);  // b * 2048 * 64 dwords

  // window skip: tiles [0, t_start) are fully masked for all 128 block rows.
  const int t_start = ((row0 * 4) / 5) >> 6;

  float psum[16];
#pragma unroll
  for (int i = 0; i < 16; ++i) psum[i] = 0.f;

  short8 kreg[4], vreg[4];

  // ======================= PASS 1: row sums =======================
#pragma unroll
  for (int i = 0; i < 4; ++i)
    kreg[i] = *(const short8*)&Kg[((size_t)t_start << 13) + ((t + (i << 8)) << 3)];
#pragma unroll
  for (int i = 0; i < 4; ++i)
    *(short8*)&Kbuf[0][(t + (i << 8)) << 3] = kreg[i];
  __syncthreads();

  for (int tt = t_start; tt < NT; ++tt) {
    const int cur = (tt - t_start) & 1;
    if (tt + 1 < NT) {  // prefetch next tile into regs (latency under compute)
#pragma unroll
      for (int i = 0; i < 4; ++i)
        kreg[i] =
            *(const short8*)&Kg[((size_t)(tt + 1) << 13) + ((t + (i << 8)) << 3)];
    }
    const int j0 = tt << 6;
#pragma unroll
    for (int jt = 0; jt < 2; ++jt) {
      const unsigned* mp =
          Mw + (((size_t)(row0 + (w << 5))) << 6) + (j0 >> 5) + jt;
      unsigned mw[16];
#pragma unroll
      for (int reg = 0; reg < 16; ++reg) {
        int rr = (reg & 3) + ((reg >> 2) << 3) + (h << 2);
        mw[reg] = mp[(size_t)rr << 6];
      }
      f32x16 c = zero16();
      __builtin_amdgcn_s_setprio(1);
#pragma unroll
      for (int kc = 0; kc < 8; ++kc) {
        short8 kb = *(const short8*)&Kbuf[cur][(((kc << 1) + h) << 9) +
                                              (((jt << 5) + l32) << 3)];
        c = __builtin_amdgcn_mfma_f32_32x32x16_bf16(qh[kc], kb, c, 0, 0, 0);
      }
      __builtin_amdgcn_s_setprio(0);
#pragma unroll
      for (int reg = 0; reg < 16; ++reg) {
        bool m = (mw[reg] >> l32) & 1u;
        float e = m ? 0.f : __expf(c[reg] * SCALE);
        psum[reg] += e;
      }
    }
    if (tt + 1 < NT) {
#pragma unroll
      for (int i = 0; i < 4; ++i)
        *(short8*)&Kbuf[cur ^ 1][(t + (i << 8)) << 3] = kreg[i];
    }
    __syncthreads();
  }

  // shuffle-reduce across 32 columns; every lane keeps its rows' inverses.
  float inv_r[16];
#pragma unroll
  for (int reg = 0; reg < 16; ++reg) {
    float ss = psum[reg];
    ss += __shfl_xor(ss, 1);  ss += __shfl_xor(ss, 2);  ss += __shfl_xor(ss, 4);
    ss += __shfl_xor(ss, 8);  ss += __shfl_xor(ss, 16);
    inv_r[reg] = 1.0f / ss;
  }

  // ======================= PASS 2: write attn + PV =======================
  f32x16 o[4];
#pragma unroll
  for (int i = 0; i < 4; ++i) o[i] = zero16();

  // prologue loads for tile t_start (issued before zero-fill to hide latency)
#pragma unroll
  for (int i = 0; i < 4; ++i) {
    kreg[i] = *(const short8*)&Kg[((size_t)t_start << 13) + ((t + (i << 8)) << 3)];
    vreg[i] = *(const short8*)&Vg[((size_t)t_start << 13) + ((t + (i << 8)) << 3)];
  }

  // zero-fill attn over the fully-window-masked tiles
  for (int tt = 0; tt < t_start; ++tt) {
    const int j0 = tt << 6;
#pragma unroll
    for (int jt = 0; jt < 2; ++jt) {
      const int jv = j0 + (jt << 5) + l32;
      const size_t abase = (((size_t)(bh << 11) + row0 + (w << 5)) << 11) + jv;
#pragma unroll
      for (int reg = 0; reg < 16; ++reg) {
        int rr = (reg & 3) + ((reg >> 2) << 3) + (h << 2);
        __builtin_nontemporal_store(0.f, &attn[abase + ((size_t)rr << 11)]);
      }
    }
  }

#pragma unroll
  for (int i = 0; i < 4; ++i) {
    *(short8*)&Kbuf[0][(t + (i << 8)) << 3] = kreg[i];
    *(short8*)&Vbuf[0][(t + (i << 8)) << 3] = vreg[i];
  }
  __syncthreads();

  for (int tt = t_start; tt < NT; ++tt) {
    const int cur = (tt - t_start) & 1;
    if (tt + 1 < NT) {
#pragma unroll
      for (int i = 0; i < 4; ++i) {
        kreg[i] =
            *(const short8*)&Kg[((size_t)(tt + 1) << 13) + ((t + (i << 8)) << 3)];
        vreg[i] =
            *(const short8*)&Vg[((size_t)(tt + 1) << 13) + ((t + (i << 8)) << 3)];
      }
    }
    const int j0 = tt << 6;
#pragma unroll
    for (int jt = 0; jt < 2; ++jt) {
      const unsigned* mp =
          Mw + (((size_t)(row0 + (w << 5))) << 6) + (j0 >> 5) + jt;
      unsigned mw[16];
#pragma unroll
      for (int reg = 0; reg < 16; ++reg) {
        int rr = (reg & 3) + ((reg >> 2) << 3) + (h << 2);
        mw[reg] = mp[(size_t)rr << 6];
      }
      f32x16 c = zero16();
      __builtin_amdgcn_s_setprio(1);
#pragma unroll
      for (int kc = 0; kc < 8; ++kc) {
        short8 kb = *(const short8*)&Kbuf[cur][(((kc << 1) + h) << 9) +
                                              (((jt << 5) + l32) << 3)];
        c = __builtin_amdgcn_mfma_f32_32x32x16_bf16(qh[kc], kb, c, 0, 0, 0);
      }
      __builtin_amdgcn_s_setprio(0);
      const int jv = j0 + (jt << 5) + l32;
      // --- compute all p first ---
      float pr[16];
#pragma unroll
      for (int reg = 0; reg < 16; ++reg) {
        bool m = (mw[reg] >> l32) & 1u;
        float e = m ? 0.f : __expf(c[reg] * SCALE);
        pr[reg] = e * inv_r[reg];
      }
      // --- batched nontemporal attn stores ---
      const size_t abase = (((size_t)(bh << 11) + row0 + (w << 5)) << 11) + jv;
#pragma unroll
      for (int reg = 0; reg < 16; ++reg) {
        int rr = (reg & 3) + ((reg >> 2) << 3) + (h << 2);
        __builtin_nontemporal_store(pr[reg], &attn[abase + ((size_t)rr << 11)]);
      }
      // --- batched Ps LDS writes (bf16 truncation, swizzled) ---
#pragma unroll
      for (int reg = 0; reg < 16; ++reg) {
        int rr = (reg & 3) + ((reg >> 2) << 3) + (h << 2);
        union { float f; unsigned u; } cc; cc.f = pr[reg];
        Ps[w][(rr << 5) + ((rr >> 2) << 3) + ((((l32 >> 3) ^ (rr & 3))) << 3) +
              (l32 & 7)] = (short)(cc.u >> 16);
      }
      // PV: o[dvt] += P(32x32) * V(32x128); V operand is one b128 each.
      __builtin_amdgcn_s_setprio(1);
#pragma unroll
      for (int kc2 = 0; kc2 < 2; ++kc2) {
        short8 pa = *(const short8*)&Ps[w][(l32 << 5) + ((l32 >> 2) << 3) +
                                           ((((kc2 << 1) + h) ^ (l32 & 3)) << 3)];
        const int jb3 = (jt << 2) + (kc2 << 1) + h;  // 8-row j-block index
#pragma unroll
        for (int dvt = 0; dvt < 4; ++dvt) {
          const int dv = (dvt << 5) + l32;
          short8 vb = *(const short8*)((const char*)&Vbuf[cur][0] + (dv << 7) +
                                       ((jb3 << 4) ^ ((l32 & 7) << 4)));
          o[dvt] = __builtin_amdgcn_mfma_f32_32x32x16_bf16(pa, vb, o[dvt], 0, 0, 0);
        }
      }
      __builtin_amdgcn_s_setprio(0);
    }
    if (tt + 1 < NT) {
#pragma unroll
      for (int i = 0; i < 4; ++i) {
        *(short8*)&Kbuf[cur ^ 1][(t + (i << 8)) << 3] = kreg[i];
        *(short8*)&Vbuf[cur ^ 1][(t + (i << 8)) << 3] = vreg[i];
      }
    }
    __syncthreads();
  }

  // ---- write context (nontemporal) ----
  const size_t cbase = ((size_t)(bh << 11) + row0 + (w << 5)) << 7;
#pragma unroll
  for (int dvt = 0; dvt < 4; ++dvt) {
#pragma unroll
    for (int reg = 0; reg < 16; ++reg) {
      int rr = (reg & 3) + ((reg >> 2) << 3) + (h << 2);
      __builtin_nontemporal_store(
          o[dvt][reg], &ctx[cbase + ((size_t)rr << 7) + (dvt << 5) + l32]);
    }
  }
}

// ---------------------------------------------------------------------------
// v3 fallback (measured 520 us): used if workspace too small for K/V packs.
// ---------------------------------------------------------------------------
__device__ __forceinline__ void kload(const float* __restrict__ Kg, int j0,
                                      int kjb, int kchunk, float4 (&kp)[8]) {
#pragma unroll
  for (int i = 0; i < 4; ++i) {
    const float* src = Kg + (size_t)(j0 + kjb + (i << 4)) * Dn + kchunk * 8;
    kp[2 * i] = *(const float4*)src;
    kp[2 * i + 1] = *(const float4*)(src + 4);
  }
}

__device__ __forceinline__ void kstore(short* Kh, int kjb, int kchunk,
                                       const float4 (&kp)[8]) {
#pragma unroll
  for (int i = 0; i < 4; ++i) {
    short8 v;
    v[0] = rne_bf16(kp[2 * i].x);     v[1] = rne_bf16(kp[2 * i].y);
    v[2] = rne_bf16(kp[2 * i].z);     v[3] = rne_bf16(kp[2 * i].w);
    v[4] = rne_bf16(kp[2 * i + 1].x); v[5] = rne_bf16(kp[2 * i + 1].y);
    v[6] = rne_bf16(kp[2 * i + 1].z); v[7] = rne_bf16(kp[2 * i + 1].w);
    *(short8*)&Kh[kchunk * 520 + (kjb + (i << 4)) * 8] = v;
  }
}

__device__ __forceinline__ void vload(const float* __restrict__ Vg, int j0,
                                      int vjb, int vdv4, float4 (&vp)[8]) {
#pragma unroll
  for (int i = 0; i < 8; ++i)
    vp[i] =
        *(const float4*)(Vg + (size_t)(j0 + (vjb << 3) + i) * Dn + (vdv4 << 2));
}

__device__ __forceinline__ void vstore(short* Vsb, int vjb, int vdv4,
                                       const float4 (&vp)[8]) {
#pragma unroll
  for (int r = 0; r < 4; ++r) {
    short8 vv;
#pragma unroll
    for (int i = 0; i < 8; ++i) {
      float f = (r == 0) ? vp[i].x
                : (r == 1) ? vp[i].y
                : (r == 2) ? vp[i].z : vp[i].w;
      vv[i] = rne_bf16(f);
    }
    const int dv = (vdv4 << 2) + r;
    *(short8*)((char*)Vsb + (dv << 7) + ((vjb << 4) ^ ((dv & 7) << 4))) = vv;
  }
}

__global__ __launch_bounds__(256, 2) void fused_attn_v3(
    const float* __restrict__ Q, const float* __restrict__ K,
    const float* __restrict__ V, const unsigned* __restrict__ mbw,
    float* __restrict__ attn, float* __restrict__ ctx) {
  const int bh = blockIdx.y, b = bh >> 4;
  const int row0 = blockIdx.x << 7;
  const int t = threadIdx.x;
  const int w = t >> 6, lane = t & 63, h = lane >> 5, l32 = lane & 31;

  __shared__ short Kh[16 * 520];
  __shared__ short Vsb[128 * 64];
  __shared__ short Ps[4][1088];

  short8 qh[8];
  {
    const float* qr = Q + (((size_t)bh << 11) + row0 + (w << 5) + l32) * Dn;
#pragma unroll
    for (int kc = 0; kc < 8; ++kc) {
      const float* p = qr + kc * 16 + h * 8;
      float4 a = *(const float4*)p, bb = *(const float4*)(p + 4);
      short8 v;
      v[0] = rne_bf16(a.x);  v[1] = rne_bf16(a.y);
      v[2] = rne_bf16(a.z);  v[3] = rne_bf16(a.w);
      v[4] = rne_bf16(bb.x); v[5] = rne_bf16(bb.y);
      v[6] = rne_bf16(bb.z); v[7] = rne_bf16(bb.w);
      qh[kc] = v;
    }
  }

  const float* Kg = K + ((size_t)bh << 11) * Dn;
  const float* Vg = V + ((size_t)bh << 11) * Dn;
  const unsigned* Mw = mbw + ((size_t)b << 17);

  const int kchunk = t & 15, kjb = t >> 4;
  const int vdv4 = t & 31, vjb = t >> 5;

  float psum[16];
#pragma unroll
  for (int i = 0; i < 16; ++i) psum[i] = 0.f;

  float4 kp[8];
  kload(Kg, 0, kjb, kchunk, kp);

  for (int j0 = 0; j0 < Sn; j0 += 64) {
    __syncthreads();
    kstore(Kh, kjb, kchunk, kp);
    __syncthreads();
    if (j0 + 64 < Sn) kload(Kg, j0 + 64, kjb, kchunk, kp);
#pragma unroll
    for (int jt = 0; jt < 2; ++jt) {
      const unsigned* mp =
          Mw + (((size_t)(row0 + (w << 5))) << 6) + (j0 >> 5) + jt;
      unsigned mw[16];
#pragma unroll
      for (int reg = 0; reg < 16; ++reg) {
        int rr = (reg & 3) + ((reg >> 2) << 3) + (h << 2);
        mw[reg] = mp[(size_t)rr << 6];
      }
      f32x16 c = zero16();
#pragma unroll
      for (int kc = 0; kc < 8; ++kc) {
        short8 kb =
            *(const short8*)&Kh[((kc << 1) + h) * 520 + ((jt << 5) + l32) * 8];
        c = __builtin_amdgcn_mfma_f32_32x32x16_bf16(qh[kc], kb, c, 0, 0, 0);
      }
#pragma unroll
      for (int reg = 0; reg < 16; ++reg) {
        bool m = (mw[reg] >> l32) & 1u;
        float e = m ? 0.f : __expf(c[reg] * SCALE);
        psum[reg] += e;
      }
    }
  }

  float inv_r[16];
#pragma unroll
  for (int reg = 0; reg < 16; ++reg) {
    float ss = psum[reg];
    ss += __shfl_xor(ss, 1);  ss += __shfl_xor(ss, 2);  ss += __shfl_xor(ss, 4);
    ss += __shfl_xor(ss, 8);  ss += __shfl_xor(ss, 16);
    inv_r[reg] = 1.0f / ss;
  }

  f32x16 o[4];
#pragma unroll
  for (int i = 0; i < 4; ++i) o[i] = zero16();

  float4 vp[8];
  kload(Kg, 0, kjb, kchunk, kp);
  vload(Vg, 0, vjb, vdv4, vp);

  for (int j0 = 0; j0 < Sn; j0 += 64) {
    __syncthreads();
    kstore(Kh, kjb, kchunk, kp);
    vstore(Vsb, vjb, vdv4, vp);
    __syncthreads();
    if (j0 + 64 < Sn) {
      kload(Kg, j0 + 64, kjb, kchunk, kp);
      vload(Vg, j0 + 64, vjb, vdv4, vp);
    }
#pragma unroll
    for (int jt = 0; jt < 2; ++jt) {
      const unsigned* mp =
          Mw + (((size_t)(row0 + (w << 5))) << 6) + (j0 >> 5) + jt;
      unsigned mw[16];
#pragma unroll
      for (int reg = 0; reg < 16; ++reg) {
        int rr = (reg & 3) + ((reg >> 2) << 3) + (h << 2);
        mw[reg] = mp[(size_t)rr << 6];
      }
      f32x16 c = zero16();
#pragma unroll
      for (int kc = 0; kc < 8; ++kc) {
        short8 kb =
            *(const short8*)&Kh[((kc << 1) + h) * 520 + ((jt << 5) + l32) * 8];
        c = __builtin_amdgcn_mfma_f32_32x32x16_bf16(qh[kc], kb, c, 0, 0, 0);
      }
      const int jv = j0 + (jt << 5) + l32;
      float pr[16];
#pragma unroll
      for (int reg = 0; reg < 16; ++reg) {
        bool m = (mw[reg] >> l32) & 1u;
        float e = m ? 0.f : __expf(c[reg] * SCALE);
        pr[reg] = e * inv_r[reg];
      }
      const size_t abase = (((size_t)(bh << 11) + row0 + (w << 5)) << 11) + jv;
#pragma unroll
      for (int reg = 0; reg < 16; ++reg) {
        int rr = (reg & 3) + ((reg >> 2) << 3) + (h << 2);
        attn[abase + ((size_t)rr << 11)] = pr[reg];
      }
#pragma unroll
      for (int reg = 0; reg < 16; ++reg) {
        int rr = (reg & 3) + ((reg >> 2) << 3) + (h << 2);
        union { float f; unsigned u; } cc; cc.f = pr[reg];
        Ps[w][(rr << 5) + ((rr >> 2) << 3) + ((((l32 >> 3) ^ (rr & 3))) << 3) +
              (l32 & 7)] = (short)(cc.u >> 16);
      }
#pragma unroll
      for (int kc2 = 0; kc2 < 2; ++kc2) {
        short8 pa = *(const short8*)&Ps[w][(l32 << 5) + ((l32 >> 2) << 3) +
                                           ((((kc2 << 1) + h) ^ (l32 & 3)) << 3)];
        const int jb3 = (jt << 2) + (kc2 << 1) + h;
#pragma unroll
        for (int dvt = 0; dvt < 4; ++dvt) {
          const int dv = (dvt << 5) + l32;
          short8 vb = *(const short8*)((const char*)Vsb + (dv << 7) +
                                       ((jb3 << 4) ^ ((l32 & 7) << 4)));
          o[dvt] = __builtin_amdgcn_mfma_f32_32x32x16_bf16(pa, vb, o[dvt], 0, 0, 0);
        }
      }
    }
  }

  const size_t cbase = ((size_t)(bh << 11) + row0 + (w << 5)) << 7;
#pragma unroll
  for (int dvt = 0; dvt < 4; ++dvt) {
#pragma unroll
    for (int reg = 0; reg < 16; ++reg) {
      int rr = (reg & 3) + ((reg >> 2) << 3) + (h << 2);
      ctx[cbase + ((size_t)rr << 7) + (dvt << 5) + l32] = o[dvt][reg];
    }
  }
}

// ---------------------------------------------------------------------------
extern "C" void kernel_launch(void* const* d_in, const int* in_sizes, int n_in,
                              void* d_out, int out_size, void* d_ws,
                              size_t ws_size, hipStream_t stream) {
  const float* Q = (const float*)d_in[0];
  const float* K = (const float*)d_in[1];
  const float* V = (const float*)d_in[2];
  const void* mask = d_in[3];

  float* out = (float*)d_out;
  float* ctx = out;                                   // B*H*S*DV
  float* attn = out + (size_t)BHn * Sn * (size_t)Dn;  // B*H*S*S

  int* mflag = (int*)d_ws;
  unsigned* bits32 = (unsigned*)((char*)d_ws + 256);
  const size_t bits_bytes = (size_t)2 * Sn * (Sn / 8);  // 1 MiB
  short* Kpk = (short*)((char*)d_ws + 256 + bits_bytes);
  const size_t pack_shorts = (size_t)BHn * NT * TILE_SHORTS;  // 8.4M shorts
  short* Vt = Kpk + pack_shorts;
  const size_t need_v5 = 256 + bits_bytes + 2 * pack_shorts * sizeof(short);

  detect_mask_kernel<<<1, 64, 0, stream>>>((const unsigned char*)mask, mflag);

  if (ws_size >= need_v5) {
    pack_mask_kernel<<<dim3(1024), 256, 0, stream>>>(
        (const unsigned char*)mask, mflag, bits32);
    pack_k_kernel<<<dim3(NT, BHn), 256, 0, stream>>>(K, Kpk);
    pack_v_kernel<<<dim3(NT, BHn), 256, 0, stream>>>(V, Vt);
    fused_attn_v5<<<dim3(512), 256, 0, stream>>>(Q, Kpk, Vt, bits32, attn,
                                                 ctx);
  } else {
    pack_mask_kernel<<<dim3(1024), 256, 0, stream>>>(
        (const unsigned char*)mask, mflag, bits32);
    fused_attn_v3<<<dim3(Sn / 128, BHn), 256, 0, stream>>>(Q, K, V, bits32,
                                                           attn, ctx);
  }
}